// Round 1
// baseline (12715.969 us; speedup 1.0000x reference)
//
#include <hip/hip_runtime.h>
#include <math.h>

#define NPAD 65

// ---------- small device helpers ----------
__device__ __forceinline__ float leaky(float x) { return x > 0.f ? x : 0.01f * x; }
__device__ __forceinline__ float eluf(float x)  { return x > 0.f ? x : (__expf(x) - 1.f); }
__device__ __forceinline__ float sigm(float x)  { return 1.f / (1.f + __expf(-x)); }
__device__ __forceinline__ float tanhfast(float x) { return 1.f - 2.f / (__expf(2.f * x) + 1.f); }

// monotone float <-> orderable-uint encoding for atomicMax on floats
__device__ __forceinline__ unsigned fenc(float f) {
    unsigned u = __float_as_uint(f);
    return (u & 0x80000000u) ? ~u : (u | 0x80000000u);
}
__device__ __forceinline__ float fdec(unsigned k) {
    return (k & 0x80000000u) ? __uint_as_float(k ^ 0x80000000u) : __uint_as_float(~k);
}

__device__ __forceinline__ void ld16(const float4* p, float* xr) {
    float4 a = p[0], b = p[1], c = p[2], d = p[3];
    xr[0]=a.x; xr[1]=a.y; xr[2]=a.z; xr[3]=a.w;
    xr[4]=b.x; xr[5]=b.y; xr[6]=b.z; xr[7]=b.w;
    xr[8]=c.x; xr[9]=c.y; xr[10]=c.z; xr[11]=c.w;
    xr[12]=d.x; xr[13]=d.y; xr[14]=d.z; xr[15]=d.w;
}

// ---------- lin1: out = leaky(in @ w^T + b), 64->64 ----------
__global__ __launch_bounds__(256) void k_dense64(
    const float* __restrict__ in, const float* __restrict__ w,
    const float* __restrict__ b, float* __restrict__ outp, int M)
{
    __shared__ float ti[64 * NPAD];
    __shared__ float to[64 * NPAD];
    int r0 = blockIdx.x * 64;
    for (int i = threadIdx.x; i < 4096; i += 256) {
        int r = i >> 6, c = i & 63; int gr = r0 + r;
        ti[r * NPAD + c] = (gr < M) ? in[(size_t)gr * 64 + c] : 0.f;
    }
    __syncthreads();
    int n = threadIdx.x & 63;
    int jl = __builtin_amdgcn_readfirstlane((threadIdx.x >> 6) << 4);
    float acc[16];
    #pragma unroll
    for (int jj = 0; jj < 16; ++jj) acc[jj] = b[jl + jj];
    for (int kc = 0; kc < 64; kc += 16) {
        float xr[16];
        #pragma unroll
        for (int i = 0; i < 16; ++i) xr[i] = ti[n * NPAD + kc + i];
        #pragma unroll
        for (int jj = 0; jj < 16; ++jj) {
            const float* wr = w + (jl + jj) * 64 + kc;
            #pragma unroll
            for (int i = 0; i < 16; ++i) acc[jj] = fmaf(wr[i], xr[i], acc[jj]);
        }
    }
    #pragma unroll
    for (int jj = 0; jj < 16; ++jj) to[n * NPAD + jl + jj] = leaky(acc[jj]);
    __syncthreads();
    for (int i = threadIdx.x; i < 4096; i += 256) {
        int r = i >> 6, c = i & 63; int gr = r0 + r;
        if (gr < M) outp[(size_t)gr * 64 + c] = to[r * NPAD + c];
    }
}

// ---------- per-node dot(s) with align vectors: s = x.wa, t = x.wb ----------
__global__ __launch_bounds__(256) void k_node_dot2(
    const float* __restrict__ x, const float* __restrict__ wa,
    const float* __restrict__ wb, float* __restrict__ s,
    float* __restrict__ t, int n, int two)
{
    int gt = blockIdx.x * 256 + threadIdx.x;
    int wid = gt >> 6, lane = threadIdx.x & 63;
    if (wid >= n) return;
    float xv = x[(size_t)wid * 64 + lane];
    float a = xv * wa[lane];
    float bb = two ? xv * wb[lane] : 0.f;
    #pragma unroll
    for (int off = 32; off; off >>= 1) {
        a  += __shfl_down(a, off);
        bb += __shfl_down(bb, off);
    }
    if (lane == 0) { s[wid] = a; if (two) t[wid] = bb; }
}

// ---------- GATE layer edge pass 1: xj GEMM + score + segment max ----------
__global__ __launch_bounds__(256) void k_gate_edge1(
    const float* __restrict__ raw, const float* __restrict__ ea, const int* __restrict__ ei,
    const float* __restrict__ wnl, const float* __restrict__ bnl,
    const float* __restrict__ gaw, const float* __restrict__ gab,
    const float* __restrict__ sarr, float* __restrict__ score,
    unsigned* __restrict__ mEnc, int E_)
{
    int e = blockIdx.x * 256 + threadIdx.x;
    if (e >= E_) return;
    int src = ei[e], dst = ei[E_ + e];
    float acc[64];
    #pragma unroll
    for (int j = 0; j < 64; ++j) acc[j] = bnl[j];
    for (int kc = 0; kc < 5; ++kc) {
        float xr[16];
        if (kc < 4) ld16((const float4*)(raw + (size_t)src * 64 + kc * 16), xr);
        else        ld16((const float4*)(ea + (size_t)e * 16), xr);
        const float* wb_ = wnl + kc * 16;
        #pragma unroll
        for (int j = 0; j < 64; ++j) {
            const float* wr = wb_ + j * 80;
            #pragma unroll
            for (int i = 0; i < 16; ++i) acc[j] = fmaf(wr[i], xr[i], acc[j]);
        }
    }
    float t = 0.f;
    #pragma unroll
    for (int j = 0; j < 64; ++j) t = fmaf(leaky(acc[j]), gaw[64 + j], t);
    float sc = leaky(sarr[dst] + t + gab[0]);
    score[e] = sc;
    atomicMax(&mEnc[dst], fenc(sc));
}

// ---------- shared edge pass 2: exp + denom ----------
__global__ __launch_bounds__(256) void k_edge_exp(
    const int* __restrict__ ei, float* __restrict__ score,
    const unsigned* __restrict__ mEnc, float* __restrict__ den, int E_)
{
    int e = blockIdx.x * 256 + threadIdx.x;
    if (e >= E_) return;
    int dst = ei[E_ + e];
    float ewv = __expf(score[e] - fdec(mEnc[dst]));
    score[e] = ewv;
    unsafeAtomicAdd(&den[dst], ewv);
}

// ---------- GATE layer edge pass 3: recompute xj, weighted scatter ----------
__global__ __launch_bounds__(256) void k_gate_edge3(
    const float* __restrict__ raw, const float* __restrict__ ea, const int* __restrict__ ei,
    const float* __restrict__ wnl, const float* __restrict__ bnl,
    const float* __restrict__ ew, const float* __restrict__ den,
    float* __restrict__ Agg, int E_)
{
    int e = blockIdx.x * 256 + threadIdx.x;
    if (e >= E_) return;
    int src = ei[e], dst = ei[E_ + e];
    float acc[64];
    #pragma unroll
    for (int j = 0; j < 64; ++j) acc[j] = bnl[j];
    for (int kc = 0; kc < 5; ++kc) {
        float xr[16];
        if (kc < 4) ld16((const float4*)(raw + (size_t)src * 64 + kc * 16), xr);
        else        ld16((const float4*)(ea + (size_t)e * 16), xr);
        const float* wb_ = wnl + kc * 16;
        #pragma unroll
        for (int j = 0; j < 64; ++j) {
            const float* wr = wb_ + j * 80;
            #pragma unroll
            for (int i = 0; i < 16; ++i) acc[j] = fmaf(wr[i], xr[i], acc[j]);
        }
    }
    float aw = ew[e] / (den[dst] + 1e-16f);
    float* ap = Agg + (size_t)dst * 64;
    #pragma unroll
    for (int j = 0; j < 64; ++j) unsafeAtomicAdd(ap + j, leaky(acc[j]) * aw);
}

// ---------- GAT layer edge pass 1: score from node dots + segment max ----------
__global__ __launch_bounds__(256) void k_gat_edge1(
    const int* __restrict__ ei, const float* __restrict__ s, const float* __restrict__ tt,
    const float* __restrict__ cb, float* __restrict__ score,
    unsigned* __restrict__ mEnc, int E_)
{
    int e = blockIdx.x * 256 + threadIdx.x;
    if (e >= E_) return;
    int src = ei[e], dst = ei[E_ + e];
    float sc = leaky(s[dst] + tt[src] + cb[0]);
    score[e] = sc;
    atomicMax(&mEnc[dst], fenc(sc));
}

// ---------- GAT layer edge pass 3: Agg[dst] += aw * x[src] ----------
__global__ __launch_bounds__(256) void k_gat_edge3(
    const int* __restrict__ ei, const float* __restrict__ x,
    const float* __restrict__ ew, const float* __restrict__ den,
    float* __restrict__ Agg, int E_)
{
    int e = blockIdx.x * 256 + threadIdx.x;
    if (e >= E_) return;
    int src = ei[e], dst = ei[E_ + e];
    float aw = ew[e] / (den[dst] + 1e-16f);
    const float4* xp = (const float4*)(x + (size_t)src * 64);
    float* ap = Agg + (size_t)dst * 64;
    #pragma unroll
    for (int q = 0; q < 16; ++q) {
        float4 v = xp[q];
        unsafeAtomicAdd(ap + q * 4 + 0, aw * v.x);
        unsafeAtomicAdd(ap + q * 4 + 1, aw * v.y);
        unsafeAtomicAdd(ap + q * 4 + 2, aw * v.z);
        unsafeAtomicAdd(ap + q * 4 + 3, aw * v.w);
    }
}

// ---------- fused node update: h = elu(Agg@Wa^T + ba); out = relu(GRU(h, x)) ----------
__global__ __launch_bounds__(256) void k_node_update(
    const float* __restrict__ agg, const float* __restrict__ xold,
    const float* __restrict__ wa, const float* __restrict__ ba,
    const float* __restrict__ wih, const float* __restrict__ whh,
    const float* __restrict__ bih, const float* __restrict__ bhh,
    float* __restrict__ xout, int M)
{
    __shared__ float tA[64 * NPAD];
    __shared__ float tX[64 * NPAD];
    __shared__ float tH[64 * NPAD];
    int r0 = blockIdx.x * 64;
    for (int i = threadIdx.x; i < 4096; i += 256) {
        int r = i >> 6, c = i & 63; int gr = r0 + r;
        float av = 0.f, xv = 0.f;
        if (gr < M) { av = agg[(size_t)gr * 64 + c]; xv = xold[(size_t)gr * 64 + c]; }
        tA[r * NPAD + c] = av; tX[r * NPAD + c] = xv;
    }
    __syncthreads();
    int n = threadIdx.x & 63;
    int jl = __builtin_amdgcn_readfirstlane((threadIdx.x >> 6) << 4);

    // Phase B: h = elu(Agg @ Wa^T + ba)
    {
        float acc[16];
        #pragma unroll
        for (int jj = 0; jj < 16; ++jj) acc[jj] = ba[jl + jj];
        for (int kc = 0; kc < 64; kc += 16) {
            float ar[16];
            #pragma unroll
            for (int i = 0; i < 16; ++i) ar[i] = tA[n * NPAD + kc + i];
            #pragma unroll
            for (int jj = 0; jj < 16; ++jj) {
                const float* wr = wa + (jl + jj) * 64 + kc;
                #pragma unroll
                for (int i = 0; i < 16; ++i) acc[jj] = fmaf(wr[i], ar[i], acc[jj]);
            }
        }
        #pragma unroll
        for (int jj = 0; jj < 16; ++jj) tH[n * NPAD + jl + jj] = eluf(acc[jj]);
    }
    __syncthreads();

    // Phase C: GRU(h, x) with 6 fused dot products per (node, j)
    float air[16], aiz[16], ain[16], ahr[16], ahz[16], ahn[16];
    #pragma unroll
    for (int jj = 0; jj < 16; ++jj) {
        air[jj] = bih[jl + jj];       ahr[jj] = bhh[jl + jj];
        aiz[jj] = bih[64 + jl + jj];  ahz[jj] = bhh[64 + jl + jj];
        ain[jj] = bih[128 + jl + jj]; ahn[jj] = bhh[128 + jl + jj];
    }
    for (int kc = 0; kc < 64; kc += 8) {
        float hr_[8], xr_[8];
        #pragma unroll
        for (int i = 0; i < 8; ++i) { hr_[i] = tH[n * NPAD + kc + i]; xr_[i] = tX[n * NPAD + kc + i]; }
        #pragma unroll
        for (int jj = 0; jj < 16; ++jj) {
            const float* w1 = wih + (jl + jj) * 64 + kc;
            const float* w2 = wih + (64 + jl + jj) * 64 + kc;
            const float* w3 = wih + (128 + jl + jj) * 64 + kc;
            const float* w4 = whh + (jl + jj) * 64 + kc;
            const float* w5 = whh + (64 + jl + jj) * 64 + kc;
            const float* w6 = whh + (128 + jl + jj) * 64 + kc;
            #pragma unroll
            for (int i = 0; i < 8; ++i) {
                air[jj] = fmaf(w1[i], hr_[i], air[jj]);
                aiz[jj] = fmaf(w2[i], hr_[i], aiz[jj]);
                ain[jj] = fmaf(w3[i], hr_[i], ain[jj]);
                ahr[jj] = fmaf(w4[i], xr_[i], ahr[jj]);
                ahz[jj] = fmaf(w5[i], xr_[i], ahz[jj]);
                ahn[jj] = fmaf(w6[i], xr_[i], ahn[jj]);
            }
        }
    }
    #pragma unroll
    for (int jj = 0; jj < 16; ++jj) {
        float r = sigm(air[jj] + ahr[jj]);
        float z = sigm(aiz[jj] + ahz[jj]);
        float nn = tanhfast(ain[jj] + r * ahn[jj]);
        float xo = tX[n * NPAD + jl + jj];
        float v = (1.f - z) * nn + z * xo;
        tA[n * NPAD + jl + jj] = fmaxf(v, 0.f);
    }
    __syncthreads();
    for (int i = threadIdx.x; i < 4096; i += 256) {
        int r = i >> 6, c = i & 63; int gr = r0 + r;
        if (gr < M) xout[(size_t)gr * 64 + c] = tA[r * NPAD + c];
    }
}

// ---------- readout: aggG[batch[n]] += x[n] (per element) ----------
__global__ __launch_bounds__(256) void k_seg_nodes(
    const float* __restrict__ x, const int* __restrict__ batch,
    float* __restrict__ aggG, int n)
{
    int idx = blockIdx.x * 256 + threadIdx.x;
    if (idx >= n * 64) return;
    int nd = idx >> 6;
    int b = batch[nd];
    unsafeAtomicAdd(&aggG[(size_t)b * 64 + (idx & 63)], x[idx]);
}

__global__ __launch_bounds__(256) void k_relu_g(
    const float* __restrict__ in, float* __restrict__ outp, int n)
{
    int idx = blockIdx.x * 256 + threadIdx.x;
    if (idx < n) outp[idx] = fmaxf(in[idx], 0.f);
}

// ---------- mol pass 1: score per node + segment max over graphs ----------
__global__ __launch_bounds__(256) void k_mol_node1(
    const float* __restrict__ xf, const float* __restrict__ cach,
    const float* __restrict__ og, const int* __restrict__ batch,
    const float* __restrict__ maw, const float* __restrict__ mab,
    float* __restrict__ scn, unsigned* __restrict__ mEg, int n)
{
    int gt = blockIdx.x * 256 + threadIdx.x;
    int wid = gt >> 6, lane = threadIdx.x & 63;
    if (wid >= n) return;
    float m = 0.5f * (xf[(size_t)wid * 64 + lane] + cach[(size_t)wid * 64 + lane]);
    float d = m * maw[64 + lane];
    #pragma unroll
    for (int off = 32; off; off >>= 1) d += __shfl_down(d, off);
    if (lane == 0) {
        int b = batch[wid];
        float sc = leaky(og[b] + d + mab[0]);
        scn[wid] = sc;
        atomicMax(&mEg[b], fenc(sc));
    }
}

__global__ __launch_bounds__(256) void k_mol_node2(
    const int* __restrict__ batch, float* __restrict__ scn,
    const unsigned* __restrict__ mEg, float* __restrict__ deng, int n)
{
    int i = blockIdx.x * 256 + threadIdx.x;
    if (i >= n) return;
    int b = batch[i];
    float ewv = __expf(scn[i] - fdec(mEg[b]));
    scn[i] = ewv;
    unsafeAtomicAdd(&deng[b], ewv);
}

__global__ __launch_bounds__(256) void k_mol_node3(
    const int* __restrict__ batch, const float* __restrict__ xf,
    const float* __restrict__ cach, const float* __restrict__ scn,
    const float* __restrict__ deng, float* __restrict__ aggG, int n)
{
    int idx = blockIdx.x * 256 + threadIdx.x;
    if (idx >= n * 64) return;
    int nd = idx >> 6;
    int b = batch[nd];
    float aw = scn[nd] / (deng[b] + 1e-16f);
    float m = 0.5f * (xf[idx] + cach[idx]);
    unsafeAtomicAdd(&aggG[(size_t)b * 64 + (idx & 63)], aw * m);
}

// ---------- final: out[g] = state[g].lin2_w + lin2_b ----------
__global__ __launch_bounds__(256) void k_lin2(
    const float* __restrict__ st, const float* __restrict__ w,
    const float* __restrict__ b, float* __restrict__ outp, int g)
{
    int gt = blockIdx.x * 256 + threadIdx.x;
    int wid = gt >> 6, lane = threadIdx.x & 63;
    if (wid >= g) return;
    float v = st[(size_t)wid * 64 + lane] * w[lane];
    #pragma unroll
    for (int off = 32; off; off >>= 1) v += __shfl_down(v, off);
    if (lane == 0) outp[wid] = v + b[0];
}

// =====================================================================
extern "C" void kernel_launch(void* const* d_in, const int* in_sizes, int n_in,
                              void* d_out, int out_size, void* d_ws, size_t ws_size,
                              hipStream_t stream) {
    const float* raw           = (const float*)d_in[0];
    const int*   ei            = (const int*)d_in[1];
    const float* ea            = (const float*)d_in[2];
    const int*   batch         = (const int*)d_in[3];
    const float* lin1_w        = (const float*)d_in[4];
    const float* lin1_b        = (const float*)d_in[5];
    const float* gate_nl_w     = (const float*)d_in[6];
    const float* gate_nl_b     = (const float*)d_in[7];
    const float* gate_align_w  = (const float*)d_in[8];
    const float* gate_align_b  = (const float*)d_in[9];
    const float* gate_attend_w = (const float*)d_in[10];
    const float* gate_attend_b = (const float*)d_in[11];
    const float* conv_align_w  = (const float*)d_in[12];
    const float* conv_align_b  = (const float*)d_in[13];
    const float* conv_attend_w = (const float*)d_in[14];
    const float* conv_attend_b = (const float*)d_in[15];
    const float* gru_wih       = (const float*)d_in[16];
    const float* gru_whh       = (const float*)d_in[17];
    const float* gru_bih       = (const float*)d_in[18];
    const float* gru_bhh       = (const float*)d_in[19];
    const float* mol_align_w   = (const float*)d_in[20];
    const float* mol_align_b   = (const float*)d_in[21];
    const float* mol_attend_w  = (const float*)d_in[22];
    const float* mol_attend_b  = (const float*)d_in[23];
    const float* mol_wih       = (const float*)d_in[24];
    const float* mol_whh       = (const float*)d_in[25];
    const float* mol_bih       = (const float*)d_in[26];
    const float* mol_bhh       = (const float*)d_in[27];
    const float* lin2_w        = (const float*)d_in[28];
    const float* lin2_b        = (const float*)d_in[29];
    float* out = (float*)d_out;

    const int N = in_sizes[3];
    const int E = in_sizes[1] / 2;
    const int G = out_size;          // OUT = 1
    const size_t N64 = (size_t)N * 64;
    const size_t G64 = (size_t)G * 64;

    // workspace layout (floats)
    float* f = (float*)d_ws;
    float* xA    = f;                 // x state / final x
    float* xB    = xA + N64;          // x after GATE layer
    float* xD    = xB + N64;          // x after GAT layer 0 (= cached[1])
    float* Agg   = xD + N64;          // edge-scatter accumulator [N,64]
    float* score = Agg + N64;         // per-edge score / exp    [E]
    float* sN    = score + E;         // per-node dst align dot  [N]
    float* tN    = sN + N;            // per-node src align dot  [N]
    float* scn   = tN + N;            // mol per-node score      [N]
    unsigned* mEnc = (unsigned*)(scn + N);   // [N]
    float* den   = (float*)(mEnc + N);       // [N]
    float* og    = den + N;                  // [G]
    unsigned* mEg = (unsigned*)(og + G);     // [G]
    float* deng  = (float*)(mEg + G);        // [G]
    float* outS  = deng + G;                 // [G,64]
    float* outS2 = outS + G64;               // [G,64]
    float* aggG  = outS2 + G64;              // [G,64]

    const int nb_node64 = (N + 63) / 64;
    const int nb_edge   = (E + 255) / 256;
    const int nb_waveN  = (N + 3) / 4;
    const int nb_elemN  = (int)((N64 + 255) / 256);
    const int nb_waveG  = (G + 3) / 4;
    const int nb_g64    = (int)((G64 + 255) / 256);
    const int nb_nodeG  = (G + 63) / 64;

    // ---- lin1 ----
    k_dense64<<<nb_node64, 256, 0, stream>>>(raw, lin1_w, lin1_b, xA, N);

    // ---- layer 0: GATEConv (xA -> xB) ----
    k_node_dot2<<<nb_waveN, 256, 0, stream>>>(xA, gate_align_w, gate_align_w, sN, tN, N, 0);
    hipMemsetAsync(mEnc, 0, (size_t)N * 4, stream);
    hipMemsetAsync(den, 0, (size_t)N * 4, stream);
    hipMemsetAsync(Agg, 0, N64 * 4, stream);
    k_gate_edge1<<<nb_edge, 256, 0, stream>>>(raw, ea, ei, gate_nl_w, gate_nl_b,
                                              gate_align_w, gate_align_b, sN, score, mEnc, E);
    k_edge_exp<<<nb_edge, 256, 0, stream>>>(ei, score, mEnc, den, E);
    k_gate_edge3<<<nb_edge, 256, 0, stream>>>(raw, ea, ei, gate_nl_w, gate_nl_b,
                                              score, den, Agg, E);
    k_node_update<<<nb_node64, 256, 0, stream>>>(Agg, xA, gate_attend_w, gate_attend_b,
                                                 gru_wih, gru_whh, gru_bih, gru_bhh, xB, N);

    // ---- GAT layer 0 (xB -> xD) ----
    k_node_dot2<<<nb_waveN, 256, 0, stream>>>(xB, conv_align_w, conv_align_w + 64, sN, tN, N, 1);
    hipMemsetAsync(mEnc, 0, (size_t)N * 4, stream);
    hipMemsetAsync(den, 0, (size_t)N * 4, stream);
    hipMemsetAsync(Agg, 0, N64 * 4, stream);
    k_gat_edge1<<<nb_edge, 256, 0, stream>>>(ei, sN, tN, conv_align_b, score, mEnc, E);
    k_edge_exp<<<nb_edge, 256, 0, stream>>>(ei, score, mEnc, den, E);
    k_gat_edge3<<<nb_edge, 256, 0, stream>>>(ei, xB, score, den, Agg, E);
    k_node_update<<<nb_node64, 256, 0, stream>>>(Agg, xB, conv_attend_w, conv_attend_b,
                                                 gru_wih + 12288, gru_whh + 12288,
                                                 gru_bih + 192, gru_bhh + 192, xD, N);

    // ---- GAT layer 1 (xD -> xA, final x) ----
    k_node_dot2<<<nb_waveN, 256, 0, stream>>>(xD, conv_align_w + 128, conv_align_w + 192, sN, tN, N, 1);
    hipMemsetAsync(mEnc, 0, (size_t)N * 4, stream);
    hipMemsetAsync(den, 0, (size_t)N * 4, stream);
    hipMemsetAsync(Agg, 0, N64 * 4, stream);
    k_gat_edge1<<<nb_edge, 256, 0, stream>>>(ei, sN, tN, conv_align_b + 1, score, mEnc, E);
    k_edge_exp<<<nb_edge, 256, 0, stream>>>(ei, score, mEnc, den, E);
    k_gat_edge3<<<nb_edge, 256, 0, stream>>>(ei, xD, score, den, Agg, E);
    k_node_update<<<nb_node64, 256, 0, stream>>>(Agg, xD, conv_attend_w + 4096, conv_attend_b + 64,
                                                 gru_wih + 24576, gru_whh + 24576,
                                                 gru_bih + 384, gru_bhh + 384, xA, N);

    // ---- molecule readout ----
    hipMemsetAsync(aggG, 0, G64 * 4, stream);
    k_seg_nodes<<<nb_elemN, 256, 0, stream>>>(xA, batch, aggG, N);
    k_relu_g<<<nb_g64, 256, 0, stream>>>(aggG, outS, (int)G64);

    const float* cachedP[2] = { xD, xA };   // cached[-2], cached[-1]
    float* sIn = outS; float* sOut = outS2;
    for (int t = 0; t < 2; ++t) {
        k_node_dot2<<<nb_waveG, 256, 0, stream>>>(sIn, mol_align_w, mol_align_w, og, og, G, 0);
        hipMemsetAsync(mEg, 0, (size_t)G * 4, stream);
        hipMemsetAsync(deng, 0, (size_t)G * 4, stream);
        hipMemsetAsync(aggG, 0, G64 * 4, stream);
        k_mol_node1<<<nb_waveN, 256, 0, stream>>>(xA, cachedP[t], og, batch,
                                                  mol_align_w, mol_align_b, scn, mEg, N);
        k_mol_node2<<<(N + 255) / 256, 256, 0, stream>>>(batch, scn, mEg, deng, N);
        k_mol_node3<<<nb_elemN, 256, 0, stream>>>(batch, xA, cachedP[t], scn, deng, aggG, N);
        k_node_update<<<nb_nodeG, 256, 0, stream>>>(aggG, sIn, mol_attend_w, mol_attend_b,
                                                    mol_wih, mol_whh, mol_bih, mol_bhh, sOut, G);
        float* tmp = sIn; sIn = sOut; sOut = tmp;
    }

    k_lin2<<<nb_waveG, 256, 0, stream>>>(sIn, lin2_w, lin2_b, out, G);
}

// Round 2
// 2634.769 us; speedup vs baseline: 4.8262x; 4.8262x over previous
//
#include <hip/hip_runtime.h>
#include <math.h>

#define NPAD 65

// ---------- small device helpers ----------
__device__ __forceinline__ float leaky(float x) { return x > 0.f ? x : 0.01f * x; }
__device__ __forceinline__ float eluf(float x)  { return x > 0.f ? x : (__expf(x) - 1.f); }
__device__ __forceinline__ float sigm(float x)  { return 1.f / (1.f + __expf(-x)); }
__device__ __forceinline__ float tanhfast(float x) { return 1.f - 2.f / (__expf(2.f * x) + 1.f); }

// uniform broadcast from lane k (k must be wave-uniform)
__device__ __forceinline__ float bcastf(float v, int k) {
    return __uint_as_float((unsigned)__builtin_amdgcn_readlane((int)__float_as_uint(v), k));
}
__device__ __forceinline__ int bcasti(int v, int k) {
    return __builtin_amdgcn_readlane(v, k);
}
__device__ __forceinline__ float wredsum(float v) {
    #pragma unroll
    for (int off = 32; off; off >>= 1) v += __shfl_xor(v, off);
    return v;
}
__device__ __forceinline__ float wredmax(float v) {
    #pragma unroll
    for (int off = 32; off; off >>= 1) v = fmaxf(v, __shfl_xor(v, off));
    return v;
}

// ================= CSR build =================
__global__ __launch_bounds__(256) void k_hist(const int* __restrict__ ei, int* __restrict__ deg, int E_) {
    int e = blockIdx.x * 256 + threadIdx.x;
    if (e < E_) atomicAdd(&deg[ei[E_ + e]], 1);
}

__global__ __launch_bounds__(256) void k_scan1(const int* __restrict__ deg, int* __restrict__ bsum, int N_) {
    __shared__ int s[256];
    int i = blockIdx.x * 256 + threadIdx.x;
    s[threadIdx.x] = (i < N_) ? deg[i] : 0;
    __syncthreads();
    for (int off = 128; off; off >>= 1) {
        if (threadIdx.x < off) s[threadIdx.x] += s[threadIdx.x + off];
        __syncthreads();
    }
    if (threadIdx.x == 0) bsum[blockIdx.x] = s[0];
}

__global__ void k_scan2(int* __restrict__ bsum, int nb) {
    if (threadIdx.x == 0 && blockIdx.x == 0) {
        int acc = 0;
        for (int i = 0; i < nb; ++i) { int v = bsum[i]; bsum[i] = acc; acc += v; }
    }
}

__global__ __launch_bounds__(256) void k_scan3(const int* __restrict__ deg, const int* __restrict__ bsum,
                                               int* __restrict__ row, int* __restrict__ cur, int N_, int E_) {
    __shared__ int s[256];
    int i = blockIdx.x * 256 + threadIdx.x;
    int d = (i < N_) ? deg[i] : 0;
    s[threadIdx.x] = d;
    __syncthreads();
    for (int off = 1; off < 256; off <<= 1) {
        int v = (threadIdx.x >= off) ? s[threadIdx.x - off] : 0;
        __syncthreads();
        s[threadIdx.x] += v;
        __syncthreads();
    }
    if (i < N_) {
        int ex = bsum[blockIdx.x] + s[threadIdx.x] - d;
        row[i] = ex; cur[i] = ex;
    }
    if (i == N_ - 1) row[N_] = E_;
}

__global__ __launch_bounds__(256) void k_scatter(const int* __restrict__ ei, int* __restrict__ cur,
                                                 int* __restrict__ csrc, int* __restrict__ ceid, int E_) {
    int e = blockIdx.x * 256 + threadIdx.x;
    if (e >= E_) return;
    int dst = ei[E_ + e];
    int slot = atomicAdd(&cur[dst], 1);
    csrc[slot] = ei[e];
    ceid[slot] = e;
}

// graph segment boundaries from sorted batch
__global__ __launch_bounds__(256) void k_gbounds(const int* __restrict__ batch, int* __restrict__ gst,
                                                 int N_, int G_) {
    int i = blockIdx.x * 256 + threadIdx.x;
    if (i >= N_) return;
    int b = batch[i];
    int prev = (i == 0) ? -1 : batch[i - 1];
    for (int g = prev + 1; g <= b; ++g) gst[g] = i;
    if (i == N_ - 1) { for (int g = b + 1; g <= G_; ++g) gst[g] = N_; }
}

// ---------- lin1: out = leaky(in @ w^T + b), 64->64 ----------
__global__ __launch_bounds__(256) void k_dense64(
    const float* __restrict__ in, const float* __restrict__ w,
    const float* __restrict__ b, float* __restrict__ outp, int M)
{
    __shared__ float ti[64 * NPAD];
    __shared__ float to[64 * NPAD];
    int r0 = blockIdx.x * 64;
    for (int i = threadIdx.x; i < 4096; i += 256) {
        int r = i >> 6, c = i & 63; int gr = r0 + r;
        ti[r * NPAD + c] = (gr < M) ? in[(size_t)gr * 64 + c] : 0.f;
    }
    __syncthreads();
    int n = threadIdx.x & 63;
    int jl = __builtin_amdgcn_readfirstlane((threadIdx.x >> 6) << 4);
    float acc[16];
    #pragma unroll
    for (int jj = 0; jj < 16; ++jj) acc[jj] = b[jl + jj];
    for (int kc = 0; kc < 64; kc += 16) {
        float xr[16];
        #pragma unroll
        for (int i = 0; i < 16; ++i) xr[i] = ti[n * NPAD + kc + i];
        #pragma unroll
        for (int jj = 0; jj < 16; ++jj) {
            const float* wr = w + (jl + jj) * 64 + kc;
            #pragma unroll
            for (int i = 0; i < 16; ++i) acc[jj] = fmaf(wr[i], xr[i], acc[jj]);
        }
    }
    #pragma unroll
    for (int jj = 0; jj < 16; ++jj) to[n * NPAD + jl + jj] = leaky(acc[jj]);
    __syncthreads();
    for (int i = threadIdx.x; i < 4096; i += 256) {
        int r = i >> 6, c = i & 63; int gr = r0 + r;
        if (gr < M) outp[(size_t)gr * 64 + c] = to[r * NPAD + c];
    }
}

// ---------- per-node dot(s) with align vectors: s = x.wa, t = x.wb ----------
__global__ __launch_bounds__(256) void k_node_dot2(
    const float* __restrict__ x, const float* __restrict__ wa,
    const float* __restrict__ wb, float* __restrict__ s,
    float* __restrict__ t, int n, int two)
{
    int gt = blockIdx.x * 256 + threadIdx.x;
    int wid = gt >> 6, lane = threadIdx.x & 63;
    if (wid >= n) return;
    float xv = x[(size_t)wid * 64 + lane];
    float a = xv * wa[lane];
    float bb = two ? xv * wb[lane] : 0.f;
    #pragma unroll
    for (int off = 32; off; off >>= 1) {
        a  += __shfl_down(a, off);
        bb += __shfl_down(bb, off);
    }
    if (lane == 0) { s[wid] = a; if (two) t[wid] = bb; }
}

// ---------- GATE layer: one wave per dst node, online softmax gather ----------
// Agg[n] = sum_e aw_e * xj_e  (attend GEMM commutes with the weighted sum)
__global__ __launch_bounds__(256) void k_gate_gather(
    const float* __restrict__ raw, const float* __restrict__ ea,
    const int* __restrict__ row, const int* __restrict__ csrc, const int* __restrict__ ceid,
    const float* __restrict__ wnl, const float* __restrict__ bnl,
    const float* __restrict__ gaw, const float* __restrict__ gab,
    const float* __restrict__ sarr, float* __restrict__ Agg, int N_)
{
    int wid = (blockIdx.x * 256 + threadIdx.x) >> 6;
    int lane = threadIdx.x & 63;
    if (wid >= N_) return;
    float wrow[80];
    #pragma unroll
    for (int k = 0; k < 80; ++k) wrow[k] = wnl[lane * 80 + k];
    float b_ = bnl[lane];
    float g2 = gaw[64 + lane];
    float gb = gab[0];
    float sdst = sarr[wid];
    int beg = row[wid], end = row[wid + 1];
    float m = -INFINITY, d = 0.f, S = 0.f;
    for (int slot = beg; slot < end; ++slot) {
        int src = csrc[slot], eid = ceid[slot];
        float r = raw[(size_t)src * 64 + lane];
        float a = (lane < 16) ? ea[(size_t)eid * 16 + lane] : 0.f;
        float a0 = b_, a1 = 0.f, a2 = 0.f, a3 = 0.f;
        #pragma unroll
        for (int k = 0; k < 64; k += 4) {
            a0 = fmaf(bcastf(r, k),     wrow[k],     a0);
            a1 = fmaf(bcastf(r, k + 1), wrow[k + 1], a1);
            a2 = fmaf(bcastf(r, k + 2), wrow[k + 2], a2);
            a3 = fmaf(bcastf(r, k + 3), wrow[k + 3], a3);
        }
        #pragma unroll
        for (int k = 0; k < 16; k += 4) {
            a0 = fmaf(bcastf(a, k),     wrow[64 + k],     a0);
            a1 = fmaf(bcastf(a, k + 1), wrow[64 + k + 1], a1);
            a2 = fmaf(bcastf(a, k + 2), wrow[64 + k + 2], a2);
            a3 = fmaf(bcastf(a, k + 3), wrow[64 + k + 3], a3);
        }
        float xj = leaky((a0 + a1) + (a2 + a3));
        float t = wredsum(xj * g2);
        float sc = leaky(sdst + t + gb);
        float mn = fmaxf(m, sc);
        float c = __expf(m - mn), w = __expf(sc - mn);
        S = S * c + w * xj;
        d = d * c + w;
        m = mn;
    }
    Agg[(size_t)wid * 64 + lane] = S / (d + 1e-16f);
}

// ---------- GAT layer: one wave per dst node, chunked online softmax gather ----------
__global__ __launch_bounds__(256) void k_gat_gather(
    const int* __restrict__ row, const int* __restrict__ csrc,
    const float* __restrict__ x, const float* __restrict__ sarr,
    const float* __restrict__ tarr, const float* __restrict__ cb,
    float* __restrict__ Agg, int N_)
{
    int wid = (blockIdx.x * 256 + threadIdx.x) >> 6;
    int lane = threadIdx.x & 63;
    if (wid >= N_) return;
    float sdst = sarr[wid];
    float cbv = cb[0];
    int beg = row[wid], end = row[wid + 1];
    float m = -INFINITY, d = 0.f, S = 0.f;
    for (int cs = beg; cs < end; cs += 64) {
        int cnt = min(64, end - cs);
        float sc_l = -INFINITY; int src_l = 0;
        if (lane < cnt) {
            src_l = csrc[cs + lane];
            sc_l = leaky(sdst + tarr[src_l] + cbv);
        }
        float cmax = wredmax(sc_l);
        float mn = fmaxf(m, cmax);
        float c = __expf(m - mn);
        float w_l = __expf(sc_l - mn);   // -inf -> 0 for invalid lanes
        float dsum = wredsum(w_l);
        d = d * c + dsum;
        S *= c;
        for (int l = 0; l < cnt; ++l) {
            float wl = bcastf(w_l, l);
            int srcl = bcasti(src_l, l);
            S = fmaf(wl, x[(size_t)srcl * 64 + lane], S);
        }
        m = mn;
    }
    Agg[(size_t)wid * 64 + lane] = S / (d + 1e-16f);
}

// ---------- fused node update: h = elu(Agg@Wa^T + ba); out = relu(GRU(h, x)) ----------
__global__ __launch_bounds__(256) void k_node_update(
    const float* __restrict__ agg, const float* __restrict__ xold,
    const float* __restrict__ wa, const float* __restrict__ ba,
    const float* __restrict__ wih, const float* __restrict__ whh,
    const float* __restrict__ bih, const float* __restrict__ bhh,
    float* __restrict__ xout, int M)
{
    __shared__ float tA[64 * NPAD];
    __shared__ float tX[64 * NPAD];
    __shared__ float tH[64 * NPAD];
    int r0 = blockIdx.x * 64;
    for (int i = threadIdx.x; i < 4096; i += 256) {
        int r = i >> 6, c = i & 63; int gr = r0 + r;
        float av = 0.f, xv = 0.f;
        if (gr < M) { av = agg[(size_t)gr * 64 + c]; xv = xold[(size_t)gr * 64 + c]; }
        tA[r * NPAD + c] = av; tX[r * NPAD + c] = xv;
    }
    __syncthreads();
    int n = threadIdx.x & 63;
    int jl = __builtin_amdgcn_readfirstlane((threadIdx.x >> 6) << 4);

    // Phase B: h = elu(Agg @ Wa^T + ba)
    {
        float acc[16];
        #pragma unroll
        for (int jj = 0; jj < 16; ++jj) acc[jj] = ba[jl + jj];
        for (int kc = 0; kc < 64; kc += 16) {
            float ar[16];
            #pragma unroll
            for (int i = 0; i < 16; ++i) ar[i] = tA[n * NPAD + kc + i];
            #pragma unroll
            for (int jj = 0; jj < 16; ++jj) {
                const float* wr = wa + (jl + jj) * 64 + kc;
                #pragma unroll
                for (int i = 0; i < 16; ++i) acc[jj] = fmaf(wr[i], ar[i], acc[jj]);
            }
        }
        #pragma unroll
        for (int jj = 0; jj < 16; ++jj) tH[n * NPAD + jl + jj] = eluf(acc[jj]);
    }
    __syncthreads();

    // Phase C: GRU(h, x)
    float air[16], aiz[16], ain[16], ahr[16], ahz[16], ahn[16];
    #pragma unroll
    for (int jj = 0; jj < 16; ++jj) {
        air[jj] = bih[jl + jj];       ahr[jj] = bhh[jl + jj];
        aiz[jj] = bih[64 + jl + jj];  ahz[jj] = bhh[64 + jl + jj];
        ain[jj] = bih[128 + jl + jj]; ahn[jj] = bhh[128 + jl + jj];
    }
    for (int kc = 0; kc < 64; kc += 8) {
        float hr_[8], xr_[8];
        #pragma unroll
        for (int i = 0; i < 8; ++i) { hr_[i] = tH[n * NPAD + kc + i]; xr_[i] = tX[n * NPAD + kc + i]; }
        #pragma unroll
        for (int jj = 0; jj < 16; ++jj) {
            const float* w1 = wih + (jl + jj) * 64 + kc;
            const float* w2 = wih + (64 + jl + jj) * 64 + kc;
            const float* w3 = wih + (128 + jl + jj) * 64 + kc;
            const float* w4 = whh + (jl + jj) * 64 + kc;
            const float* w5 = whh + (64 + jl + jj) * 64 + kc;
            const float* w6 = whh + (128 + jl + jj) * 64 + kc;
            #pragma unroll
            for (int i = 0; i < 8; ++i) {
                air[jj] = fmaf(w1[i], hr_[i], air[jj]);
                aiz[jj] = fmaf(w2[i], hr_[i], aiz[jj]);
                ain[jj] = fmaf(w3[i], hr_[i], ain[jj]);
                ahr[jj] = fmaf(w4[i], xr_[i], ahr[jj]);
                ahz[jj] = fmaf(w5[i], xr_[i], ahz[jj]);
                ahn[jj] = fmaf(w6[i], xr_[i], ahn[jj]);
            }
        }
    }
    #pragma unroll
    for (int jj = 0; jj < 16; ++jj) {
        float r = sigm(air[jj] + ahr[jj]);
        float z = sigm(aiz[jj] + ahz[jj]);
        float nn = tanhfast(ain[jj] + r * ahn[jj]);
        float xo = tX[n * NPAD + jl + jj];
        float v = (1.f - z) * nn + z * xo;
        tA[n * NPAD + jl + jj] = fmaxf(v, 0.f);
    }
    __syncthreads();
    for (int i = threadIdx.x; i < 4096; i += 256) {
        int r = i >> 6, c = i & 63; int gr = r0 + r;
        if (gr < M) xout[(size_t)gr * 64 + c] = tA[r * NPAD + c];
    }
}

// ---------- readout: wave per graph, contiguous segment sum + relu ----------
__global__ __launch_bounds__(256) void k_seg_sum_relu(
    const float* __restrict__ x, const int* __restrict__ gst,
    float* __restrict__ outp, int G_)
{
    int g = (blockIdx.x * 256 + threadIdx.x) >> 6;
    int lane = threadIdx.x & 63;
    if (g >= G_) return;
    float S = 0.f;
    int end = gst[g + 1];
    for (int i = gst[g]; i < end; ++i) S += x[(size_t)i * 64 + lane];
    outp[(size_t)g * 64 + lane] = fmaxf(S, 0.f);
}

// ---------- molecule attention: wave per graph, online softmax gather ----------
__global__ __launch_bounds__(256) void k_mol_gather(
    const float* __restrict__ xf, const float* __restrict__ cach,
    const float* __restrict__ stateIn, const int* __restrict__ gst,
    const float* __restrict__ maw, const float* __restrict__ mab,
    float* __restrict__ Agg, int G_)
{
    int g = (blockIdx.x * 256 + threadIdx.x) >> 6;
    int lane = threadIdx.x & 63;
    if (g >= G_) return;
    float o = stateIn[(size_t)g * 64 + lane];
    float og = wredsum(o * maw[lane]);
    float m2 = maw[64 + lane];
    float mb = mab[0];
    int beg = gst[g], end = gst[g + 1];
    float m = -INFINITY, d = 0.f, S = 0.f;
    for (int i = beg; i < end; ++i) {
        float mix = 0.5f * (xf[(size_t)i * 64 + lane] + cach[(size_t)i * 64 + lane]);
        float dd = wredsum(mix * m2);
        float sc = leaky(og + dd + mb);
        float mn = fmaxf(m, sc);
        float c = __expf(m - mn), w = __expf(sc - mn);
        S = S * c + w * mix;
        d = d * c + w;
        m = mn;
    }
    Agg[(size_t)g * 64 + lane] = S / (d + 1e-16f);
}

// ---------- final: out[g] = state[g].lin2_w + lin2_b ----------
__global__ __launch_bounds__(256) void k_lin2(
    const float* __restrict__ st, const float* __restrict__ w,
    const float* __restrict__ b, float* __restrict__ outp, int g)
{
    int gt = blockIdx.x * 256 + threadIdx.x;
    int wid = gt >> 6, lane = threadIdx.x & 63;
    if (wid >= g) return;
    float v = st[(size_t)wid * 64 + lane] * w[lane];
    #pragma unroll
    for (int off = 32; off; off >>= 1) v += __shfl_down(v, off);
    if (lane == 0) outp[wid] = v + b[0];
}

// =====================================================================
extern "C" void kernel_launch(void* const* d_in, const int* in_sizes, int n_in,
                              void* d_out, int out_size, void* d_ws, size_t ws_size,
                              hipStream_t stream) {
    const float* raw           = (const float*)d_in[0];
    const int*   ei            = (const int*)d_in[1];
    const float* ea            = (const float*)d_in[2];
    const int*   batch         = (const int*)d_in[3];
    const float* lin1_w        = (const float*)d_in[4];
    const float* lin1_b        = (const float*)d_in[5];
    const float* gate_nl_w     = (const float*)d_in[6];
    const float* gate_nl_b     = (const float*)d_in[7];
    const float* gate_align_w  = (const float*)d_in[8];
    const float* gate_align_b  = (const float*)d_in[9];
    const float* gate_attend_w = (const float*)d_in[10];
    const float* gate_attend_b = (const float*)d_in[11];
    const float* conv_align_w  = (const float*)d_in[12];
    const float* conv_align_b  = (const float*)d_in[13];
    const float* conv_attend_w = (const float*)d_in[14];
    const float* conv_attend_b = (const float*)d_in[15];
    const float* gru_wih       = (const float*)d_in[16];
    const float* gru_whh       = (const float*)d_in[17];
    const float* gru_bih       = (const float*)d_in[18];
    const float* gru_bhh       = (const float*)d_in[19];
    const float* mol_align_w   = (const float*)d_in[20];
    const float* mol_align_b   = (const float*)d_in[21];
    const float* mol_attend_w  = (const float*)d_in[22];
    const float* mol_attend_b  = (const float*)d_in[23];
    const float* mol_wih       = (const float*)d_in[24];
    const float* mol_whh       = (const float*)d_in[25];
    const float* mol_bih       = (const float*)d_in[26];
    const float* mol_bhh       = (const float*)d_in[27];
    const float* lin2_w        = (const float*)d_in[28];
    const float* lin2_b        = (const float*)d_in[29];
    float* out = (float*)d_out;

    const int N = in_sizes[3];
    const int E = in_sizes[1] / 2;
    const int G = out_size;
    const size_t N64 = (size_t)N * 64;
    const size_t G64 = (size_t)G * 64;

    // ---- workspace layout ----
    float* f = (float*)d_ws;
    float* xA    = f;                 // node state
    float* xB    = xA + N64;          // after GATE layer (cached[0])
    float* xD    = xB + N64;          // after GAT layer 0 (cached[1])
    float* Agg   = xD + N64;          // gather result [N,64]
    float* sN    = Agg + N64;         // per-node dst align dot [N]
    float* tN    = sN + N;            // per-node src align dot [N]
    float* outS  = tN + N;            // graph state A [G,64]
    float* outS2 = outS + G64;        // graph state B [G,64]
    float* aggG  = outS2 + G64;       // graph gather  [G,64]
    int* row  = (int*)(aggG + G64);   // [N+1]
    int* csrc = row + (N + 1);        // [E]
    int* ceid = csrc + E;             // [E]
    int* bsum = ceid + E;             // [512]
    int* gst  = bsum + 512;           // [G+1]
    // deg/cur alias Agg (consumed before Agg's first write)
    int* deg = (int*)Agg;
    int* cur = deg + N;

    const int nb_node64 = (N + 63) / 64;
    const int nb_edge   = (E + 255) / 256;
    const int nb_nodes  = (N + 255) / 256;      // 1 thread/node
    const int nb_waveN  = (N + 3) / 4;          // 1 wave/node
    const int nb_waveG  = (G + 3) / 4;
    const int nb_nodeG  = (G + 63) / 64;

    // ---- CSR build (dst-sorted adjacency) ----
    hipMemsetAsync(deg, 0, (size_t)N * 4, stream);
    k_hist<<<nb_edge, 256, 0, stream>>>(ei, deg, E);
    k_scan1<<<nb_nodes, 256, 0, stream>>>(deg, bsum, N);
    k_scan2<<<1, 64, 0, stream>>>(bsum, nb_nodes);
    k_scan3<<<nb_nodes, 256, 0, stream>>>(deg, bsum, row, cur, N, E);
    k_scatter<<<nb_edge, 256, 0, stream>>>(ei, cur, csrc, ceid, E);
    k_gbounds<<<nb_nodes, 256, 0, stream>>>(batch, gst, N, G);

    // ---- lin1 ----
    k_dense64<<<nb_node64, 256, 0, stream>>>(raw, lin1_w, lin1_b, xA, N);

    // ---- layer 0: GATEConv (xA -> xB) ----
    k_node_dot2<<<nb_waveN, 256, 0, stream>>>(xA, gate_align_w, gate_align_w, sN, tN, N, 0);
    k_gate_gather<<<nb_waveN, 256, 0, stream>>>(raw, ea, row, csrc, ceid,
                                                gate_nl_w, gate_nl_b, gate_align_w, gate_align_b,
                                                sN, Agg, N);
    k_node_update<<<nb_node64, 256, 0, stream>>>(Agg, xA, gate_attend_w, gate_attend_b,
                                                 gru_wih, gru_whh, gru_bih, gru_bhh, xB, N);

    // ---- GAT layer 0 (xB -> xD) ----
    k_node_dot2<<<nb_waveN, 256, 0, stream>>>(xB, conv_align_w, conv_align_w + 64, sN, tN, N, 1);
    k_gat_gather<<<nb_waveN, 256, 0, stream>>>(row, csrc, xB, sN, tN, conv_align_b, Agg, N);
    k_node_update<<<nb_node64, 256, 0, stream>>>(Agg, xB, conv_attend_w, conv_attend_b,
                                                 gru_wih + 12288, gru_whh + 12288,
                                                 gru_bih + 192, gru_bhh + 192, xD, N);

    // ---- GAT layer 1 (xD -> xA) ----
    k_node_dot2<<<nb_waveN, 256, 0, stream>>>(xD, conv_align_w + 128, conv_align_w + 192, sN, tN, N, 1);
    k_gat_gather<<<nb_waveN, 256, 0, stream>>>(row, csrc, xD, sN, tN, conv_align_b + 1, Agg, N);
    k_node_update<<<nb_node64, 256, 0, stream>>>(Agg, xD, conv_attend_w + 4096, conv_attend_b + 64,
                                                 gru_wih + 24576, gru_whh + 24576,
                                                 gru_bih + 384, gru_bhh + 384, xA, N);

    // ---- molecule readout ----
    k_seg_sum_relu<<<nb_waveG, 256, 0, stream>>>(xA, gst, outS, G);

    const float* cachedP[2] = { xD, xA };   // cached[-2], cached[-1]
    float* sIn = outS; float* sOut = outS2;
    for (int t = 0; t < 2; ++t) {
        k_mol_gather<<<nb_waveN, 256, 0, stream>>>(xA, cachedP[t], sIn, gst,
                                                   mol_align_w, mol_align_b, aggG, G);
        k_node_update<<<nb_nodeG, 256, 0, stream>>>(aggG, sIn, mol_attend_w, mol_attend_b,
                                                    mol_wih, mol_whh, mol_bih, mol_bhh, sOut, G);
        float* tmp = sIn; sIn = sOut; sOut = tmp;
    }

    k_lin2<<<nb_waveG, 256, 0, stream>>>(sIn, lin2_w, lin2_b, out, G);
}

// Round 3
// 2232.134 us; speedup vs baseline: 5.6968x; 1.1804x over previous
//
#include <hip/hip_runtime.h>
#include <math.h>

#define NPAD 65

// ---------- small device helpers ----------
__device__ __forceinline__ float leaky(float x) { return x > 0.f ? x : 0.01f * x; }
__device__ __forceinline__ float eluf(float x)  { return x > 0.f ? x : (__expf(x) - 1.f); }
__device__ __forceinline__ float sigm(float x)  { return 1.f / (1.f + __expf(-x)); }
__device__ __forceinline__ float tanhfast(float x) { return 1.f - 2.f / (__expf(2.f * x) + 1.f); }

__device__ __forceinline__ float bcastf(float v, int k) {
    return __uint_as_float((unsigned)__builtin_amdgcn_readlane((int)__float_as_uint(v), k));
}
__device__ __forceinline__ int bcasti(int v, int k) {
    return __builtin_amdgcn_readlane(v, k);
}
__device__ __forceinline__ float wredsum(float v) {
    #pragma unroll
    for (int off = 32; off; off >>= 1) v += __shfl_xor(v, off);
    return v;
}
__device__ __forceinline__ float wredmax(float v) {
    #pragma unroll
    for (int off = 32; off; off >>= 1) v = fmaxf(v, __shfl_xor(v, off));
    return v;
}

// ================= CSR build =================
__global__ __launch_bounds__(256) void k_hist(const int* __restrict__ ei, int* __restrict__ deg, int E_) {
    int e = blockIdx.x * 256 + threadIdx.x;
    if (e < E_) atomicAdd(&deg[ei[E_ + e]], 1);
}

__global__ __launch_bounds__(256) void k_scan1(const int* __restrict__ deg, int* __restrict__ bsum, int N_) {
    __shared__ int s[256];
    int i = blockIdx.x * 256 + threadIdx.x;
    s[threadIdx.x] = (i < N_) ? deg[i] : 0;
    __syncthreads();
    for (int off = 128; off; off >>= 1) {
        if (threadIdx.x < off) s[threadIdx.x] += s[threadIdx.x + off];
        __syncthreads();
    }
    if (threadIdx.x == 0) bsum[blockIdx.x] = s[0];
}

__global__ void k_scan2(int* __restrict__ bsum, int nb) {
    if (threadIdx.x == 0 && blockIdx.x == 0) {
        int acc = 0;
        for (int i = 0; i < nb; ++i) { int v = bsum[i]; bsum[i] = acc; acc += v; }
    }
}

__global__ __launch_bounds__(256) void k_scan3(const int* __restrict__ deg, const int* __restrict__ bsum,
                                               int* __restrict__ row, int* __restrict__ cur, int N_, int E_) {
    __shared__ int s[256];
    int i = blockIdx.x * 256 + threadIdx.x;
    int d = (i < N_) ? deg[i] : 0;
    s[threadIdx.x] = d;
    __syncthreads();
    for (int off = 1; off < 256; off <<= 1) {
        int v = (threadIdx.x >= off) ? s[threadIdx.x - off] : 0;
        __syncthreads();
        s[threadIdx.x] += v;
        __syncthreads();
    }
    if (i < N_) {
        int ex = bsum[blockIdx.x] + s[threadIdx.x] - d;
        row[i] = ex; cur[i] = ex;
    }
    if (i == N_ - 1) row[N_] = E_;
}

__global__ __launch_bounds__(256) void k_scatter(const int* __restrict__ ei, int* __restrict__ cur,
                                                 int* __restrict__ csrc, int* __restrict__ ceid, int E_) {
    int e = blockIdx.x * 256 + threadIdx.x;
    if (e >= E_) return;
    int dst = ei[E_ + e];
    int slot = atomicAdd(&cur[dst], 1);
    csrc[slot] = ei[e];
    ceid[slot] = e;
}

__global__ __launch_bounds__(256) void k_gbounds(const int* __restrict__ batch, int* __restrict__ gst,
                                                 int N_, int G_) {
    int i = blockIdx.x * 256 + threadIdx.x;
    if (i >= N_) return;
    int b = batch[i];
    int prev = (i == 0) ? -1 : batch[i - 1];
    for (int g = prev + 1; g <= b; ++g) gst[g] = i;
    if (i == N_ - 1) { for (int g = b + 1; g <= G_; ++g) gst[g] = N_; }
}

// ---------- dense64: out = act(in @ w^T + b), w row-stride = wstride ----------
__global__ __launch_bounds__(256) void k_dense64(
    const float* __restrict__ in, const float* __restrict__ w, int wstride,
    const float* __restrict__ b, float* __restrict__ outp, int M, int act)
{
    __shared__ float ti[64 * NPAD];
    __shared__ float to[64 * NPAD];
    int r0 = blockIdx.x * 64;
    for (int i = threadIdx.x; i < 4096; i += 256) {
        int r = i >> 6, c = i & 63; int gr = r0 + r;
        ti[r * NPAD + c] = (gr < M) ? in[(size_t)gr * 64 + c] : 0.f;
    }
    __syncthreads();
    int n = threadIdx.x & 63;
    int jl = __builtin_amdgcn_readfirstlane((threadIdx.x >> 6) << 4);
    float acc[16];
    #pragma unroll
    for (int jj = 0; jj < 16; ++jj) acc[jj] = b[jl + jj];
    for (int kc = 0; kc < 64; kc += 16) {
        float xr[16];
        #pragma unroll
        for (int i = 0; i < 16; ++i) xr[i] = ti[n * NPAD + kc + i];
        #pragma unroll
        for (int jj = 0; jj < 16; ++jj) {
            const float* wr = w + (jl + jj) * wstride + kc;
            #pragma unroll
            for (int i = 0; i < 16; ++i) acc[jj] = fmaf(wr[i], xr[i], acc[jj]);
        }
    }
    #pragma unroll
    for (int jj = 0; jj < 16; ++jj) {
        float v = acc[jj];
        to[n * NPAD + jl + jj] = act ? leaky(v) : v;
    }
    __syncthreads();
    for (int i = threadIdx.x; i < 4096; i += 256) {
        int r = i >> 6, c = i & 63; int gr = r0 + r;
        if (gr < M) outp[(size_t)gr * 64 + c] = to[r * NPAD + c];
    }
}

// ---------- per-node dot(s) with align vectors ----------
__global__ __launch_bounds__(256) void k_node_dot2(
    const float* __restrict__ x, const float* __restrict__ wa,
    const float* __restrict__ wb, float* __restrict__ s,
    float* __restrict__ t, int n, int two)
{
    int gt = blockIdx.x * 256 + threadIdx.x;
    int wid = gt >> 6, lane = threadIdx.x & 63;
    if (wid >= n) return;
    float xv = x[(size_t)wid * 64 + lane];
    float a = xv * wa[lane];
    float bb = two ? xv * wb[lane] : 0.f;
    #pragma unroll
    for (int off = 32; off; off >>= 1) {
        a  += __shfl_down(a, off);
        bb += __shfl_down(bb, off);
    }
    if (lane == 0) { s[wid] = a; if (two) t[wid] = bb; }
}

// ---------- GATE layer: wave per dst node, online softmax gather ----------
// xj_e = leaky(u[src] + W2 @ ea[e]);  u precomputed = raw@W1^T + b
__global__ __launch_bounds__(256) void k_gate_gather(
    const float* __restrict__ u, const float* __restrict__ ea,
    const int* __restrict__ row, const int* __restrict__ csrc, const int* __restrict__ ceid,
    const float* __restrict__ wnl,
    const float* __restrict__ gaw, const float* __restrict__ gab,
    const float* __restrict__ sarr, float* __restrict__ Agg, int N_)
{
    int wid = (blockIdx.x * 256 + threadIdx.x) >> 6;
    int lane = threadIdx.x & 63;
    if (wid >= N_) return;
    float w2[16];
    #pragma unroll
    for (int k = 0; k < 16; ++k) w2[k] = wnl[lane * 80 + 64 + k];
    float g2 = gaw[64 + lane];
    float gb = gab[0];
    float sdst = sarr[wid];
    int beg = row[wid], end = row[wid + 1];
    float m = -INFINITY, d = 0.f, S = 0.f;
    for (int cs = beg; cs < end; cs += 64) {
        int cnt = min(64, end - cs);
        int src_l = 0, eid_l = 0;
        if (lane < cnt) { src_l = csrc[cs + lane]; eid_l = ceid[cs + lane]; }
        for (int l = 0; l < cnt; ++l) {
            int src = bcasti(src_l, l), eid = bcasti(eid_l, l);
            float acc = u[(size_t)src * 64 + lane];
            const float* er = ea + (size_t)eid * 16;
            #pragma unroll
            for (int k = 0; k < 16; ++k) acc = fmaf(er[k], w2[k], acc);
            float xj = leaky(acc);
            float t = wredsum(xj * g2);
            float sc = leaky(sdst + t + gb);
            float mn = fmaxf(m, sc);
            float c = __expf(m - mn), w = __expf(sc - mn);
            S = S * c + w * xj;
            d = d * c + w;
            m = mn;
        }
    }
    Agg[(size_t)wid * 64 + lane] = S / (d + 1e-16f);
}

// ---------- GAT layer: wave per dst node, chunked online softmax gather ----------
__global__ __launch_bounds__(256) void k_gat_gather(
    const int* __restrict__ row, const int* __restrict__ csrc,
    const float* __restrict__ x, const float* __restrict__ sarr,
    const float* __restrict__ tarr, const float* __restrict__ cb,
    float* __restrict__ Agg, int N_)
{
    int wid = (blockIdx.x * 256 + threadIdx.x) >> 6;
    int lane = threadIdx.x & 63;
    if (wid >= N_) return;
    float sdst = sarr[wid];
    float cbv = cb[0];
    int beg = row[wid], end = row[wid + 1];
    float m = -INFINITY, d = 0.f, S = 0.f;
    for (int cs = beg; cs < end; cs += 64) {
        int cnt = min(64, end - cs);
        float sc_l = -INFINITY; int src_l = 0;
        if (lane < cnt) {
            src_l = csrc[cs + lane];
            sc_l = leaky(sdst + tarr[src_l] + cbv);
        }
        float cmax = wredmax(sc_l);
        float mn = fmaxf(m, cmax);
        float c = __expf(m - mn);
        float w_l = __expf(sc_l - mn);
        d = d * c + wredsum(w_l);
        S *= c;
        int l = 0;
        for (; l + 4 <= cnt; l += 4) {
            int s0 = bcasti(src_l, l), s1 = bcasti(src_l, l + 1);
            int s2 = bcasti(src_l, l + 2), s3 = bcasti(src_l, l + 3);
            float w0 = bcastf(w_l, l), w1 = bcastf(w_l, l + 1);
            float w2 = bcastf(w_l, l + 2), w3 = bcastf(w_l, l + 3);
            float r0 = x[(size_t)s0 * 64 + lane];
            float r1 = x[(size_t)s1 * 64 + lane];
            float r2 = x[(size_t)s2 * 64 + lane];
            float r3 = x[(size_t)s3 * 64 + lane];
            S = fmaf(w0, r0, S); S = fmaf(w1, r1, S);
            S = fmaf(w2, r2, S); S = fmaf(w3, r3, S);
        }
        for (; l < cnt; ++l) {
            float wl = bcastf(w_l, l);
            int srcl = bcasti(src_l, l);
            S = fmaf(wl, x[(size_t)srcl * 64 + lane], S);
        }
        m = mn;
    }
    Agg[(size_t)wid * 64 + lane] = S / (d + 1e-16f);
}

// ---------- fused node update: h = elu(Agg@Wa^T + ba); out = relu(GRU(h, x)) ----------
__global__ __launch_bounds__(256) void k_node_update(
    const float* __restrict__ agg, const float* __restrict__ xold,
    const float* __restrict__ wa, const float* __restrict__ ba,
    const float* __restrict__ wih, const float* __restrict__ whh,
    const float* __restrict__ bih, const float* __restrict__ bhh,
    float* __restrict__ xout, int M)
{
    __shared__ float tA[64 * NPAD];
    __shared__ float tX[64 * NPAD];
    __shared__ float tH[64 * NPAD];
    int r0 = blockIdx.x * 64;
    for (int i = threadIdx.x; i < 4096; i += 256) {
        int r = i >> 6, c = i & 63; int gr = r0 + r;
        float av = 0.f, xv = 0.f;
        if (gr < M) { av = agg[(size_t)gr * 64 + c]; xv = xold[(size_t)gr * 64 + c]; }
        tA[r * NPAD + c] = av; tX[r * NPAD + c] = xv;
    }
    __syncthreads();
    int n = threadIdx.x & 63;
    int jl = __builtin_amdgcn_readfirstlane((threadIdx.x >> 6) << 4);

    {
        float acc[16];
        #pragma unroll
        for (int jj = 0; jj < 16; ++jj) acc[jj] = ba[jl + jj];
        for (int kc = 0; kc < 64; kc += 16) {
            float ar[16];
            #pragma unroll
            for (int i = 0; i < 16; ++i) ar[i] = tA[n * NPAD + kc + i];
            #pragma unroll
            for (int jj = 0; jj < 16; ++jj) {
                const float* wr = wa + (jl + jj) * 64 + kc;
                #pragma unroll
                for (int i = 0; i < 16; ++i) acc[jj] = fmaf(wr[i], ar[i], acc[jj]);
            }
        }
        #pragma unroll
        for (int jj = 0; jj < 16; ++jj) tH[n * NPAD + jl + jj] = eluf(acc[jj]);
    }
    __syncthreads();

    float air[16], aiz[16], ain[16], ahr[16], ahz[16], ahn[16];
    #pragma unroll
    for (int jj = 0; jj < 16; ++jj) {
        air[jj] = bih[jl + jj];       ahr[jj] = bhh[jl + jj];
        aiz[jj] = bih[64 + jl + jj];  ahz[jj] = bhh[64 + jl + jj];
        ain[jj] = bih[128 + jl + jj]; ahn[jj] = bhh[128 + jl + jj];
    }
    for (int kc = 0; kc < 64; kc += 8) {
        float hr_[8], xr_[8];
        #pragma unroll
        for (int i = 0; i < 8; ++i) { hr_[i] = tH[n * NPAD + kc + i]; xr_[i] = tX[n * NPAD + kc + i]; }
        #pragma unroll
        for (int jj = 0; jj < 16; ++jj) {
            const float* w1 = wih + (jl + jj) * 64 + kc;
            const float* w2 = wih + (64 + jl + jj) * 64 + kc;
            const float* w3 = wih + (128 + jl + jj) * 64 + kc;
            const float* w4 = whh + (jl + jj) * 64 + kc;
            const float* w5 = whh + (64 + jl + jj) * 64 + kc;
            const float* w6 = whh + (128 + jl + jj) * 64 + kc;
            #pragma unroll
            for (int i = 0; i < 8; ++i) {
                air[jj] = fmaf(w1[i], hr_[i], air[jj]);
                aiz[jj] = fmaf(w2[i], hr_[i], aiz[jj]);
                ain[jj] = fmaf(w3[i], hr_[i], ain[jj]);
                ahr[jj] = fmaf(w4[i], xr_[i], ahr[jj]);
                ahz[jj] = fmaf(w5[i], xr_[i], ahz[jj]);
                ahn[jj] = fmaf(w6[i], xr_[i], ahn[jj]);
            }
        }
    }
    #pragma unroll
    for (int jj = 0; jj < 16; ++jj) {
        float r = sigm(air[jj] + ahr[jj]);
        float z = sigm(aiz[jj] + ahz[jj]);
        float nn = tanhfast(ain[jj] + r * ahn[jj]);
        float xo = tX[n * NPAD + jl + jj];
        float v = (1.f - z) * nn + z * xo;
        tA[n * NPAD + jl + jj] = fmaxf(v, 0.f);
    }
    __syncthreads();
    for (int i = threadIdx.x; i < 4096; i += 256) {
        int r = i >> 6, c = i & 63; int gr = r0 + r;
        if (gr < M) xout[(size_t)gr * 64 + c] = tA[r * NPAD + c];
    }
}

// ---------- readout: wave per graph, contiguous segment sum + relu ----------
__global__ __launch_bounds__(256) void k_seg_sum_relu(
    const float* __restrict__ x, const int* __restrict__ gst,
    float* __restrict__ outp, int G_)
{
    int g = (blockIdx.x * 256 + threadIdx.x) >> 6;
    int lane = threadIdx.x & 63;
    if (g >= G_) return;
    float S = 0.f;
    int end = gst[g + 1];
    for (int i = gst[g]; i < end; ++i) S += x[(size_t)i * 64 + lane];
    outp[(size_t)g * 64 + lane] = fmaxf(S, 0.f);
}

// ---------- mol: per-node dot of mix with align part 2 ----------
__global__ __launch_bounds__(256) void k_mol_dots(
    const float* __restrict__ xf, const float* __restrict__ cach,
    const float* __restrict__ maw, float* __restrict__ dd, int n)
{
    int wid = (blockIdx.x * 256 + threadIdx.x) >> 6;
    int lane = threadIdx.x & 63;
    if (wid >= n) return;
    float mix = 0.5f * (xf[(size_t)wid * 64 + lane] + cach[(size_t)wid * 64 + lane]);
    float v = wredsum(mix * maw[64 + lane]);
    if (lane == 0) dd[wid] = v;
}

// ---------- molecule attention: wave per graph, chunked online softmax ----------
__global__ __launch_bounds__(256) void k_mol_gather(
    const float* __restrict__ xf, const float* __restrict__ cach,
    const float* __restrict__ stateIn, const int* __restrict__ gst,
    const float* __restrict__ dd,
    const float* __restrict__ maw, const float* __restrict__ mab,
    float* __restrict__ Agg, int G_)
{
    int g = (blockIdx.x * 256 + threadIdx.x) >> 6;
    int lane = threadIdx.x & 63;
    if (g >= G_) return;
    float o = stateIn[(size_t)g * 64 + lane];
    float og = wredsum(o * maw[lane]);
    float mb = mab[0];
    int beg = gst[g], end = gst[g + 1];
    float m = -INFINITY, d = 0.f, S = 0.f;
    for (int cs = beg; cs < end; cs += 64) {
        int cnt = min(64, end - cs);
        float sc_l = -INFINITY;
        if (lane < cnt) sc_l = leaky(og + dd[cs + lane] + mb);
        float cmax = wredmax(sc_l);
        float mn = fmaxf(m, cmax);
        float c = __expf(m - mn);
        float w_l = __expf(sc_l - mn);
        d = d * c + wredsum(w_l);
        S *= c;
        int l = 0;
        for (; l + 4 <= cnt; l += 4) {
            float w0 = bcastf(w_l, l), w1 = bcastf(w_l, l + 1);
            float w2 = bcastf(w_l, l + 2), w3 = bcastf(w_l, l + 3);
            size_t r = (size_t)(cs + l) * 64 + lane;
            float m0 = 0.5f * (xf[r] + cach[r]);
            float m1 = 0.5f * (xf[r + 64] + cach[r + 64]);
            float m2 = 0.5f * (xf[r + 128] + cach[r + 128]);
            float m3 = 0.5f * (xf[r + 192] + cach[r + 192]);
            S = fmaf(w0, m0, S); S = fmaf(w1, m1, S);
            S = fmaf(w2, m2, S); S = fmaf(w3, m3, S);
        }
        for (; l < cnt; ++l) {
            float wl = bcastf(w_l, l);
            size_t r = (size_t)(cs + l) * 64 + lane;
            S = fmaf(wl, 0.5f * (xf[r] + cach[r]), S);
        }
        m = mn;
    }
    Agg[(size_t)g * 64 + lane] = S / (d + 1e-16f);
}

// ---------- final: out[g] = state[g].lin2_w + lin2_b ----------
__global__ __launch_bounds__(256) void k_lin2(
    const float* __restrict__ st, const float* __restrict__ w,
    const float* __restrict__ b, float* __restrict__ outp, int g)
{
    int gt = blockIdx.x * 256 + threadIdx.x;
    int wid = gt >> 6, lane = threadIdx.x & 63;
    if (wid >= g) return;
    float v = st[(size_t)wid * 64 + lane] * w[lane];
    #pragma unroll
    for (int off = 32; off; off >>= 1) v += __shfl_down(v, off);
    if (lane == 0) outp[wid] = v + b[0];
}

// =====================================================================
extern "C" void kernel_launch(void* const* d_in, const int* in_sizes, int n_in,
                              void* d_out, int out_size, void* d_ws, size_t ws_size,
                              hipStream_t stream) {
    const float* raw           = (const float*)d_in[0];
    const int*   ei            = (const int*)d_in[1];
    const float* ea            = (const float*)d_in[2];
    const int*   batch         = (const int*)d_in[3];
    const float* lin1_w        = (const float*)d_in[4];
    const float* lin1_b        = (const float*)d_in[5];
    const float* gate_nl_w     = (const float*)d_in[6];
    const float* gate_nl_b     = (const float*)d_in[7];
    const float* gate_align_w  = (const float*)d_in[8];
    const float* gate_align_b  = (const float*)d_in[9];
    const float* gate_attend_w = (const float*)d_in[10];
    const float* gate_attend_b = (const float*)d_in[11];
    const float* conv_align_w  = (const float*)d_in[12];
    const float* conv_align_b  = (const float*)d_in[13];
    const float* conv_attend_w = (const float*)d_in[14];
    const float* conv_attend_b = (const float*)d_in[15];
    const float* gru_wih       = (const float*)d_in[16];
    const float* gru_whh       = (const float*)d_in[17];
    const float* gru_bih       = (const float*)d_in[18];
    const float* gru_bhh       = (const float*)d_in[19];
    const float* mol_align_w   = (const float*)d_in[20];
    const float* mol_align_b   = (const float*)d_in[21];
    const float* mol_attend_w  = (const float*)d_in[22];
    const float* mol_attend_b  = (const float*)d_in[23];
    const float* mol_wih       = (const float*)d_in[24];
    const float* mol_whh       = (const float*)d_in[25];
    const float* mol_bih       = (const float*)d_in[26];
    const float* mol_bhh       = (const float*)d_in[27];
    const float* lin2_w        = (const float*)d_in[28];
    const float* lin2_b        = (const float*)d_in[29];
    float* out = (float*)d_out;

    const int N = in_sizes[3];
    const int E = in_sizes[1] / 2;
    const int G = out_size;
    const size_t N64 = (size_t)N * 64;
    const size_t G64 = (size_t)G * 64;

    // ---- workspace layout ----
    float* f = (float*)d_ws;
    float* xA    = f;                 // node state
    float* xB    = xA + N64;          // after GATE layer (cached[0])
    float* xD    = xB + N64;          // after GAT layer 0 (cached[1])
    float* Agg   = xD + N64;          // gather result [N,64]
    float* u     = Agg + N64;         // gate node-part precompute [N,64]
    float* sN    = u + N64;           // per-node dst align dot [N]
    float* tN    = sN + N;            // per-node src align dot [N]
    float* dd    = tN + N;            // mol per-node dot [N]
    float* outS  = dd + N;            // graph state A [G,64]
    float* outS2 = outS + G64;        // graph state B [G,64]
    float* aggG  = outS2 + G64;       // graph gather  [G,64]
    int* row  = (int*)(aggG + G64);   // [N+1]
    int* csrc = row + (N + 1);        // [E]
    int* ceid = csrc + E;             // [E]
    int* bsum = ceid + E;             // [512]
    int* gst  = bsum + 512;           // [G+1]
    // deg/cur alias Agg (consumed before Agg's first write)
    int* deg = (int*)Agg;
    int* cur = deg + N;

    const int nb_node64 = (N + 63) / 64;
    const int nb_edge   = (E + 255) / 256;
    const int nb_nodes  = (N + 255) / 256;
    const int nb_waveN  = (N + 3) / 4;
    const int nb_waveG  = (G + 3) / 4;
    const int nb_nodeG  = (G + 63) / 64;

    // ---- CSR build ----
    hipMemsetAsync(deg, 0, (size_t)N * 4, stream);
    k_hist<<<nb_edge, 256, 0, stream>>>(ei, deg, E);
    k_scan1<<<nb_nodes, 256, 0, stream>>>(deg, bsum, N);
    k_scan2<<<1, 64, 0, stream>>>(bsum, nb_nodes);
    k_scan3<<<nb_nodes, 256, 0, stream>>>(deg, bsum, row, cur, N, E);
    k_scatter<<<nb_edge, 256, 0, stream>>>(ei, cur, csrc, ceid, E);
    k_gbounds<<<nb_nodes, 256, 0, stream>>>(batch, gst, N, G);

    // ---- lin1 + gate node-part precompute ----
    k_dense64<<<nb_node64, 256, 0, stream>>>(raw, lin1_w, 64, lin1_b, xA, N, 1);
    k_dense64<<<nb_node64, 256, 0, stream>>>(raw, gate_nl_w, 80, gate_nl_b, u, N, 0);

    // ---- layer 0: GATEConv (xA -> xB) ----
    k_node_dot2<<<nb_waveN, 256, 0, stream>>>(xA, gate_align_w, gate_align_w, sN, tN, N, 0);
    k_gate_gather<<<nb_waveN, 256, 0, stream>>>(u, ea, row, csrc, ceid,
                                                gate_nl_w, gate_align_w, gate_align_b,
                                                sN, Agg, N);
    k_node_update<<<nb_node64, 256, 0, stream>>>(Agg, xA, gate_attend_w, gate_attend_b,
                                                 gru_wih, gru_whh, gru_bih, gru_bhh, xB, N);

    // ---- GAT layer 0 (xB -> xD) ----
    k_node_dot2<<<nb_waveN, 256, 0, stream>>>(xB, conv_align_w, conv_align_w + 64, sN, tN, N, 1);
    k_gat_gather<<<nb_waveN, 256, 0, stream>>>(row, csrc, xB, sN, tN, conv_align_b, Agg, N);
    k_node_update<<<nb_node64, 256, 0, stream>>>(Agg, xB, conv_attend_w, conv_attend_b,
                                                 gru_wih + 12288, gru_whh + 12288,
                                                 gru_bih + 192, gru_bhh + 192, xD, N);

    // ---- GAT layer 1 (xD -> xA) ----
    k_node_dot2<<<nb_waveN, 256, 0, stream>>>(xD, conv_align_w + 128, conv_align_w + 192, sN, tN, N, 1);
    k_gat_gather<<<nb_waveN, 256, 0, stream>>>(row, csrc, xD, sN, tN, conv_align_b + 1, Agg, N);
    k_node_update<<<nb_node64, 256, 0, stream>>>(Agg, xD, conv_attend_w + 4096, conv_attend_b + 64,
                                                 gru_wih + 24576, gru_whh + 24576,
                                                 gru_bih + 384, gru_bhh + 384, xA, N);

    // ---- molecule readout ----
    k_seg_sum_relu<<<nb_waveG, 256, 0, stream>>>(xA, gst, outS, G);

    const float* cachedP[2] = { xD, xA };   // cached[-2], cached[-1]
    float* sIn = outS; float* sOut = outS2;
    for (int t = 0; t < 2; ++t) {
        k_mol_dots<<<nb_waveN, 256, 0, stream>>>(xA, cachedP[t], mol_align_w, dd, N);
        k_mol_gather<<<nb_waveG, 256, 0, stream>>>(xA, cachedP[t], sIn, gst, dd,
                                                   mol_align_w, mol_align_b, aggG, G);
        k_node_update<<<nb_nodeG, 256, 0, stream>>>(aggG, sIn, mol_attend_w, mol_attend_b,
                                                    mol_wih, mol_whh, mol_bih, mol_bhh, sOut, G);
        float* tmp = sIn; sIn = sOut; sOut = tmp;
    }

    k_lin2<<<nb_waveG, 256, 0, stream>>>(sIn, lin2_w, lin2_b, out, G);
}

// Round 4
// 1616.058 us; speedup vs baseline: 7.8685x; 1.3812x over previous
//
#include <hip/hip_runtime.h>
#include <math.h>

#define NPAD 65

// ---------- small device helpers ----------
__device__ __forceinline__ float leaky(float x) { return x > 0.f ? x : 0.01f * x; }
__device__ __forceinline__ float eluf(float x)  { return x > 0.f ? x : (__expf(x) - 1.f); }
__device__ __forceinline__ float sigm(float x)  { return 1.f / (1.f + __expf(-x)); }
__device__ __forceinline__ float tanhfast(float x) { return 1.f - 2.f / (__expf(2.f * x) + 1.f); }

__device__ __forceinline__ float bcastf(float v, int k) {
    return __uint_as_float((unsigned)__builtin_amdgcn_readlane((int)__float_as_uint(v), k));
}
__device__ __forceinline__ int bcasti(int v, int k) {
    return __builtin_amdgcn_readlane(v, k);
}
__device__ __forceinline__ float wredsum(float v) {
    #pragma unroll
    for (int off = 32; off; off >>= 1) v += __shfl_xor(v, off);
    return v;
}
__device__ __forceinline__ float wredmax(float v) {
    #pragma unroll
    for (int off = 32; off; off >>= 1) v = fmaxf(v, __shfl_xor(v, off));
    return v;
}

// ================= CSR build =================
__global__ __launch_bounds__(256) void k_hist(const int* __restrict__ ei, int* __restrict__ deg, int E_) {
    int e = blockIdx.x * 256 + threadIdx.x;
    if (e < E_) atomicAdd(&deg[ei[E_ + e]], 1);
}

__global__ __launch_bounds__(256) void k_scan1(const int* __restrict__ deg, int* __restrict__ bsum, int N_) {
    __shared__ int s[256];
    int i = blockIdx.x * 256 + threadIdx.x;
    s[threadIdx.x] = (i < N_) ? deg[i] : 0;
    __syncthreads();
    for (int off = 128; off; off >>= 1) {
        if (threadIdx.x < off) s[threadIdx.x] += s[threadIdx.x + off];
        __syncthreads();
    }
    if (threadIdx.x == 0) bsum[blockIdx.x] = s[0];
}

__global__ void k_scan2(int* __restrict__ bsum, int nb) {
    if (threadIdx.x == 0 && blockIdx.x == 0) {
        int acc = 0;
        for (int i = 0; i < nb; ++i) { int v = bsum[i]; bsum[i] = acc; acc += v; }
    }
}

__global__ __launch_bounds__(256) void k_scan3(const int* __restrict__ deg, const int* __restrict__ bsum,
                                               int* __restrict__ row, int* __restrict__ cur, int N_, int E_) {
    __shared__ int s[256];
    int i = blockIdx.x * 256 + threadIdx.x;
    int d = (i < N_) ? deg[i] : 0;
    s[threadIdx.x] = d;
    __syncthreads();
    for (int off = 1; off < 256; off <<= 1) {
        int v = (threadIdx.x >= off) ? s[threadIdx.x - off] : 0;
        __syncthreads();
        s[threadIdx.x] += v;
        __syncthreads();
    }
    if (i < N_) {
        int ex = bsum[blockIdx.x] + s[threadIdx.x] - d;
        row[i] = ex; cur[i] = ex;
    }
    if (i == N_ - 1) row[N_] = E_;
}

__global__ __launch_bounds__(256) void k_scatter(const int* __restrict__ ei, int* __restrict__ cur,
                                                 int* __restrict__ csrc, int* __restrict__ ceid, int E_) {
    int e = blockIdx.x * 256 + threadIdx.x;
    if (e >= E_) return;
    int dst = ei[E_ + e];
    int slot = atomicAdd(&cur[dst], 1);
    csrc[slot] = ei[e];
    ceid[slot] = e;
}

__global__ __launch_bounds__(256) void k_gbounds(const int* __restrict__ batch, int* __restrict__ gst,
                                                 int N_, int G_) {
    int i = blockIdx.x * 256 + threadIdx.x;
    if (i >= N_) return;
    int b = batch[i];
    int prev = (i == 0) ? -1 : batch[i - 1];
    for (int g = prev + 1; g <= b; ++g) gst[g] = i;
    if (i == N_ - 1) { for (int g = b + 1; g <= G_; ++g) gst[g] = N_; }
}

// ---------- dense64: out = act(in @ w^T + b), w row-stride = wstride ----------
__global__ __launch_bounds__(256) void k_dense64(
    const float* __restrict__ in, const float* __restrict__ w, int wstride,
    const float* __restrict__ b, float* __restrict__ outp, int M, int act)
{
    __shared__ float ti[64 * NPAD];
    __shared__ float to[64 * NPAD];
    int r0 = blockIdx.x * 64;
    for (int i = threadIdx.x; i < 4096; i += 256) {
        int r = i >> 6, c = i & 63; int gr = r0 + r;
        ti[r * NPAD + c] = (gr < M) ? in[(size_t)gr * 64 + c] : 0.f;
    }
    __syncthreads();
    int n = threadIdx.x & 63;
    int jl = __builtin_amdgcn_readfirstlane((threadIdx.x >> 6) << 4);
    float acc[16];
    #pragma unroll
    for (int jj = 0; jj < 16; ++jj) acc[jj] = b[jl + jj];
    for (int kc = 0; kc < 64; kc += 16) {
        float xr[16];
        #pragma unroll
        for (int i = 0; i < 16; ++i) xr[i] = ti[n * NPAD + kc + i];
        #pragma unroll
        for (int jj = 0; jj < 16; ++jj) {
            const float* wr = w + (jl + jj) * wstride + kc;
            #pragma unroll
            for (int i = 0; i < 16; ++i) acc[jj] = fmaf(wr[i], xr[i], acc[jj]);
        }
    }
    #pragma unroll
    for (int jj = 0; jj < 16; ++jj) {
        float v = acc[jj];
        to[n * NPAD + jl + jj] = act ? leaky(v) : v;
    }
    __syncthreads();
    for (int i = threadIdx.x; i < 4096; i += 256) {
        int r = i >> 6, c = i & 63; int gr = r0 + r;
        if (gr < M) outp[(size_t)gr * 64 + c] = to[r * NPAD + c];
    }
}

// ---------- per-node dot(s) with align vectors ----------
__global__ __launch_bounds__(256) void k_node_dot2(
    const float* __restrict__ x, const float* __restrict__ wa,
    const float* __restrict__ wb, float* __restrict__ s,
    float* __restrict__ t, int n, int two)
{
    int gt = blockIdx.x * 256 + threadIdx.x;
    int wid = gt >> 6, lane = threadIdx.x & 63;
    if (wid >= n) return;
    float xv = x[(size_t)wid * 64 + lane];
    float a = xv * wa[lane];
    float bb = two ? xv * wb[lane] : 0.f;
    #pragma unroll
    for (int off = 32; off; off >>= 1) {
        a  += __shfl_down(a, off);
        bb += __shfl_down(bb, off);
    }
    if (lane == 0) { s[wid] = a; if (two) t[wid] = bb; }
}

// ---------- GATE layer: wave per dst node, online softmax gather ----------
__global__ __launch_bounds__(256) void k_gate_gather(
    const float* __restrict__ u, const float* __restrict__ ea,
    const int* __restrict__ row, const int* __restrict__ csrc, const int* __restrict__ ceid,
    const float* __restrict__ wnl,
    const float* __restrict__ gaw, const float* __restrict__ gab,
    const float* __restrict__ sarr, float* __restrict__ Agg, int N_)
{
    int wid = (blockIdx.x * 256 + threadIdx.x) >> 6;
    int lane = threadIdx.x & 63;
    if (wid >= N_) return;
    float w2[16];
    #pragma unroll
    for (int k = 0; k < 16; ++k) w2[k] = wnl[lane * 80 + 64 + k];
    float g2 = gaw[64 + lane];
    float gb = gab[0];
    float sdst = sarr[wid];
    int beg = row[wid], end = row[wid + 1];
    float m = -INFINITY, d = 0.f, S = 0.f;
    for (int cs = beg; cs < end; cs += 64) {
        int cnt = min(64, end - cs);
        int src_l = 0, eid_l = 0;
        if (lane < cnt) { src_l = csrc[cs + lane]; eid_l = ceid[cs + lane]; }
        for (int l = 0; l < cnt; ++l) {
            int src = bcasti(src_l, l), eid = bcasti(eid_l, l);
            float acc = u[(size_t)src * 64 + lane];
            const float* er = ea + (size_t)eid * 16;
            #pragma unroll
            for (int k = 0; k < 16; ++k) acc = fmaf(er[k], w2[k], acc);
            float xj = leaky(acc);
            float t = wredsum(xj * g2);
            float sc = leaky(sdst + t + gb);
            float mn = fmaxf(m, sc);
            float c = __expf(m - mn), w = __expf(sc - mn);
            S = S * c + w * xj;
            d = d * c + w;
            m = mn;
        }
    }
    Agg[(size_t)wid * 64 + lane] = S / (d + 1e-16f);
}

// ---------- GAT layer: wave per dst node, chunked online softmax gather ----------
__global__ __launch_bounds__(256) void k_gat_gather(
    const int* __restrict__ row, const int* __restrict__ csrc,
    const float* __restrict__ x, const float* __restrict__ sarr,
    const float* __restrict__ tarr, const float* __restrict__ cb,
    float* __restrict__ Agg, int N_)
{
    int wid = (blockIdx.x * 256 + threadIdx.x) >> 6;
    int lane = threadIdx.x & 63;
    if (wid >= N_) return;
    float sdst = sarr[wid];
    float cbv = cb[0];
    int beg = row[wid], end = row[wid + 1];
    float m = -INFINITY, d = 0.f, S = 0.f;
    for (int cs = beg; cs < end; cs += 64) {
        int cnt = min(64, end - cs);
        float sc_l = -INFINITY; int src_l = 0;
        if (lane < cnt) {
            src_l = csrc[cs + lane];
            sc_l = leaky(sdst + tarr[src_l] + cbv);
        }
        float cmax = wredmax(sc_l);
        float mn = fmaxf(m, cmax);
        float c = __expf(m - mn);
        float w_l = __expf(sc_l - mn);
        d = d * c + wredsum(w_l);
        S *= c;
        int l = 0;
        for (; l + 4 <= cnt; l += 4) {
            int s0 = bcasti(src_l, l), s1 = bcasti(src_l, l + 1);
            int s2 = bcasti(src_l, l + 2), s3 = bcasti(src_l, l + 3);
            float w0 = bcastf(w_l, l), w1 = bcastf(w_l, l + 1);
            float w2 = bcastf(w_l, l + 2), w3 = bcastf(w_l, l + 3);
            float r0 = x[(size_t)s0 * 64 + lane];
            float r1 = x[(size_t)s1 * 64 + lane];
            float r2 = x[(size_t)s2 * 64 + lane];
            float r3 = x[(size_t)s3 * 64 + lane];
            S = fmaf(w0, r0, S); S = fmaf(w1, r1, S);
            S = fmaf(w2, r2, S); S = fmaf(w3, r3, S);
        }
        for (; l < cnt; ++l) {
            float wl = bcastf(w_l, l);
            int srcl = bcasti(src_l, l);
            S = fmaf(wl, x[(size_t)srcl * 64 + lane], S);
        }
        m = mn;
    }
    Agg[(size_t)wid * 64 + lane] = S / (d + 1e-16f);
}

// ---------- fused node update (512 thr, 8 j/thread, fused r/z accumulators) ----------
// h = elu(Agg@Wa^T + ba); out = relu(GRU(h, x))
__global__ __launch_bounds__(512) void k_node_update(
    const float* __restrict__ agg, const float* __restrict__ xold,
    const float* __restrict__ wa, const float* __restrict__ ba,
    const float* __restrict__ wih, const float* __restrict__ whh,
    const float* __restrict__ bih, const float* __restrict__ bhh,
    float* __restrict__ xout, int M)
{
    __shared__ float tA[64 * NPAD];   // agg tile, then h tile, then out tile
    __shared__ float tX[64 * NPAD];   // xold tile
    int r0 = blockIdx.x * 64;
    for (int i = threadIdx.x; i < 4096; i += 512) {
        int r = i >> 6, c = i & 63; int gr = r0 + r;
        float av = 0.f, xv = 0.f;
        if (gr < M) { av = agg[(size_t)gr * 64 + c]; xv = xold[(size_t)gr * 64 + c]; }
        tA[r * NPAD + c] = av; tX[r * NPAD + c] = xv;
    }
    __syncthreads();
    int n = threadIdx.x & 63;
    int jl = __builtin_amdgcn_readfirstlane((threadIdx.x >> 6) << 3);  // 0..56

    // Phase B: h[jl..jl+8) = elu(Agg @ Wa^T + ba)
    float hv[8];
    {
        float acc[8];
        #pragma unroll
        for (int jj = 0; jj < 8; ++jj) acc[jj] = ba[jl + jj];
        for (int kc = 0; kc < 64; kc += 16) {
            float ar[16];
            #pragma unroll
            for (int i = 0; i < 16; ++i) ar[i] = tA[n * NPAD + kc + i];
            #pragma unroll
            for (int jj = 0; jj < 8; ++jj) {
                const float* wr = wa + (jl + jj) * 64 + kc;
                #pragma unroll
                for (int i = 0; i < 16; ++i) acc[jj] = fmaf(wr[i], ar[i], acc[jj]);
            }
        }
        #pragma unroll
        for (int jj = 0; jj < 8; ++jj) hv[jj] = eluf(acc[jj]);
    }
    __syncthreads();          // all phase-B reads of tA done
    #pragma unroll
    for (int jj = 0; jj < 8; ++jj) tA[n * NPAD + jl + jj] = hv[jj];
    __syncthreads();          // h tile visible

    // Phase C: GRU. r/z accumulate both input+hidden streams in one register.
    float a_r[8], a_z[8], a_n[8], a_h[8];
    #pragma unroll
    for (int jj = 0; jj < 8; ++jj) {
        a_r[jj] = bih[jl + jj] + bhh[jl + jj];
        a_z[jj] = bih[64 + jl + jj] + bhh[64 + jl + jj];
        a_n[jj] = bih[128 + jl + jj];
        a_h[jj] = bhh[128 + jl + jj];
    }
    for (int kc = 0; kc < 64; kc += 8) {
        float hr_[8], xr_[8];
        #pragma unroll
        for (int i = 0; i < 8; ++i) { hr_[i] = tA[n * NPAD + kc + i]; xr_[i] = tX[n * NPAD + kc + i]; }
        #pragma unroll
        for (int jj = 0; jj < 8; ++jj) {
            const float* w1 = wih + (jl + jj) * 64 + kc;          // r, input
            const float* w4 = whh + (jl + jj) * 64 + kc;          // r, hidden
            const float* w2 = wih + (64 + jl + jj) * 64 + kc;     // z, input
            const float* w5 = whh + (64 + jl + jj) * 64 + kc;     // z, hidden
            const float* w3 = wih + (128 + jl + jj) * 64 + kc;    // n, input
            const float* w6 = whh + (128 + jl + jj) * 64 + kc;    // n, hidden
            #pragma unroll
            for (int i = 0; i < 8; ++i) {
                a_r[jj] = fmaf(w1[i], hr_[i], a_r[jj]);
                a_r[jj] = fmaf(w4[i], xr_[i], a_r[jj]);
                a_z[jj] = fmaf(w2[i], hr_[i], a_z[jj]);
                a_z[jj] = fmaf(w5[i], xr_[i], a_z[jj]);
                a_n[jj] = fmaf(w3[i], hr_[i], a_n[jj]);
                a_h[jj] = fmaf(w6[i], xr_[i], a_h[jj]);
            }
        }
    }
    #pragma unroll
    for (int jj = 0; jj < 8; ++jj) {
        float r = sigm(a_r[jj]);
        float z = sigm(a_z[jj]);
        float nn = tanhfast(a_n[jj] + r * a_h[jj]);
        float xo = tX[n * NPAD + jl + jj];
        float v = (1.f - z) * nn + z * xo;
        hv[jj] = fmaxf(v, 0.f);
    }
    __syncthreads();          // all phase-C reads of tA done
    #pragma unroll
    for (int jj = 0; jj < 8; ++jj) tA[n * NPAD + jl + jj] = hv[jj];
    __syncthreads();
    for (int i = threadIdx.x; i < 4096; i += 512) {
        int r = i >> 6, c = i & 63; int gr = r0 + r;
        if (gr < M) xout[(size_t)gr * 64 + c] = tA[r * NPAD + c];
    }
}

// ---------- readout: wave per graph, contiguous segment sum + relu ----------
__global__ __launch_bounds__(256) void k_seg_sum_relu(
    const float* __restrict__ x, const int* __restrict__ gst,
    float* __restrict__ outp, int G_)
{
    int g = (blockIdx.x * 256 + threadIdx.x) >> 6;
    int lane = threadIdx.x & 63;
    if (g >= G_) return;
    float S = 0.f;
    int end = gst[g + 1];
    for (int i = gst[g]; i < end; ++i) S += x[(size_t)i * 64 + lane];
    outp[(size_t)g * 64 + lane] = fmaxf(S, 0.f);
}

// ---------- mol: per-node dot of mix with align part 2 ----------
__global__ __launch_bounds__(256) void k_mol_dots(
    const float* __restrict__ xf, const float* __restrict__ cach,
    const float* __restrict__ maw, float* __restrict__ dd, int n)
{
    int wid = (blockIdx.x * 256 + threadIdx.x) >> 6;
    int lane = threadIdx.x & 63;
    if (wid >= n) return;
    float mix = 0.5f * (xf[(size_t)wid * 64 + lane] + cach[(size_t)wid * 64 + lane]);
    float v = wredsum(mix * maw[64 + lane]);
    if (lane == 0) dd[wid] = v;
}

// ---------- molecule attention: wave per graph, chunked online softmax ----------
__global__ __launch_bounds__(256) void k_mol_gather(
    const float* __restrict__ xf, const float* __restrict__ cach,
    const float* __restrict__ stateIn, const int* __restrict__ gst,
    const float* __restrict__ dd,
    const float* __restrict__ maw, const float* __restrict__ mab,
    float* __restrict__ Agg, int G_)
{
    int g = (blockIdx.x * 256 + threadIdx.x) >> 6;
    int lane = threadIdx.x & 63;
    if (g >= G_) return;
    float o = stateIn[(size_t)g * 64 + lane];
    float og = wredsum(o * maw[lane]);
    float mb = mab[0];
    int beg = gst[g], end = gst[g + 1];
    float m = -INFINITY, d = 0.f, S = 0.f;
    for (int cs = beg; cs < end; cs += 64) {
        int cnt = min(64, end - cs);
        float sc_l = -INFINITY;
        if (lane < cnt) sc_l = leaky(og + dd[cs + lane] + mb);
        float cmax = wredmax(sc_l);
        float mn = fmaxf(m, cmax);
        float c = __expf(m - mn);
        float w_l = __expf(sc_l - mn);
        d = d * c + wredsum(w_l);
        S *= c;
        int l = 0;
        for (; l + 4 <= cnt; l += 4) {
            float w0 = bcastf(w_l, l), w1 = bcastf(w_l, l + 1);
            float w2 = bcastf(w_l, l + 2), w3 = bcastf(w_l, l + 3);
            size_t r = (size_t)(cs + l) * 64 + lane;
            float m0 = 0.5f * (xf[r] + cach[r]);
            float m1 = 0.5f * (xf[r + 64] + cach[r + 64]);
            float m2 = 0.5f * (xf[r + 128] + cach[r + 128]);
            float m3 = 0.5f * (xf[r + 192] + cach[r + 192]);
            S = fmaf(w0, m0, S); S = fmaf(w1, m1, S);
            S = fmaf(w2, m2, S); S = fmaf(w3, m3, S);
        }
        for (; l < cnt; ++l) {
            float wl = bcastf(w_l, l);
            size_t r = (size_t)(cs + l) * 64 + lane;
            S = fmaf(wl, 0.5f * (xf[r] + cach[r]), S);
        }
        m = mn;
    }
    Agg[(size_t)g * 64 + lane] = S / (d + 1e-16f);
}

// ---------- final: out[g] = state[g].lin2_w + lin2_b ----------
__global__ __launch_bounds__(256) void k_lin2(
    const float* __restrict__ st, const float* __restrict__ w,
    const float* __restrict__ b, float* __restrict__ outp, int g)
{
    int gt = blockIdx.x * 256 + threadIdx.x;
    int wid = gt >> 6, lane = threadIdx.x & 63;
    if (wid >= g) return;
    float v = st[(size_t)wid * 64 + lane] * w[lane];
    #pragma unroll
    for (int off = 32; off; off >>= 1) v += __shfl_down(v, off);
    if (lane == 0) outp[wid] = v + b[0];
}

// =====================================================================
extern "C" void kernel_launch(void* const* d_in, const int* in_sizes, int n_in,
                              void* d_out, int out_size, void* d_ws, size_t ws_size,
                              hipStream_t stream) {
    const float* raw           = (const float*)d_in[0];
    const int*   ei            = (const int*)d_in[1];
    const float* ea            = (const float*)d_in[2];
    const int*   batch         = (const int*)d_in[3];
    const float* lin1_w        = (const float*)d_in[4];
    const float* lin1_b        = (const float*)d_in[5];
    const float* gate_nl_w     = (const float*)d_in[6];
    const float* gate_nl_b     = (const float*)d_in[7];
    const float* gate_align_w  = (const float*)d_in[8];
    const float* gate_align_b  = (const float*)d_in[9];
    const float* gate_attend_w = (const float*)d_in[10];
    const float* gate_attend_b = (const float*)d_in[11];
    const float* conv_align_w  = (const float*)d_in[12];
    const float* conv_align_b  = (const float*)d_in[13];
    const float* conv_attend_w = (const float*)d_in[14];
    const float* conv_attend_b = (const float*)d_in[15];
    const float* gru_wih       = (const float*)d_in[16];
    const float* gru_whh       = (const float*)d_in[17];
    const float* gru_bih       = (const float*)d_in[18];
    const float* gru_bhh       = (const float*)d_in[19];
    const float* mol_align_w   = (const float*)d_in[20];
    const float* mol_align_b   = (const float*)d_in[21];
    const float* mol_attend_w  = (const float*)d_in[22];
    const float* mol_attend_b  = (const float*)d_in[23];
    const float* mol_wih       = (const float*)d_in[24];
    const float* mol_whh       = (const float*)d_in[25];
    const float* mol_bih       = (const float*)d_in[26];
    const float* mol_bhh       = (const float*)d_in[27];
    const float* lin2_w        = (const float*)d_in[28];
    const float* lin2_b        = (const float*)d_in[29];
    float* out = (float*)d_out;

    const int N = in_sizes[3];
    const int E = in_sizes[1] / 2;
    const int G = out_size;
    const size_t N64 = (size_t)N * 64;
    const size_t G64 = (size_t)G * 64;

    // ---- workspace layout ----
    float* f = (float*)d_ws;
    float* xA    = f;
    float* xB    = xA + N64;
    float* xD    = xB + N64;
    float* Agg   = xD + N64;
    float* u     = Agg + N64;
    float* sN    = u + N64;
    float* tN    = sN + N;
    float* dd    = tN + N;
    float* outS  = dd + N;
    float* outS2 = outS + G64;
    float* aggG  = outS2 + G64;
    int* row  = (int*)(aggG + G64);
    int* csrc = row + (N + 1);
    int* ceid = csrc + E;
    int* bsum = ceid + E;
    int* gst  = bsum + 512;
    int* deg = (int*)Agg;
    int* cur = deg + N;

    const int nb_node64 = (N + 63) / 64;
    const int nb_edge   = (E + 255) / 256;
    const int nb_nodes  = (N + 255) / 256;
    const int nb_waveN  = (N + 3) / 4;
    const int nb_waveG  = (G + 3) / 4;
    const int nb_nodeG  = (G + 63) / 64;

    // ---- CSR build ----
    hipMemsetAsync(deg, 0, (size_t)N * 4, stream);
    k_hist<<<nb_edge, 256, 0, stream>>>(ei, deg, E);
    k_scan1<<<nb_nodes, 256, 0, stream>>>(deg, bsum, N);
    k_scan2<<<1, 64, 0, stream>>>(bsum, nb_nodes);
    k_scan3<<<nb_nodes, 256, 0, stream>>>(deg, bsum, row, cur, N, E);
    k_scatter<<<nb_edge, 256, 0, stream>>>(ei, cur, csrc, ceid, E);
    k_gbounds<<<nb_nodes, 256, 0, stream>>>(batch, gst, N, G);

    // ---- lin1 + gate node-part precompute ----
    k_dense64<<<nb_node64, 256, 0, stream>>>(raw, lin1_w, 64, lin1_b, xA, N, 1);
    k_dense64<<<nb_node64, 256, 0, stream>>>(raw, gate_nl_w, 80, gate_nl_b, u, N, 0);

    // ---- layer 0: GATEConv (xA -> xB) ----
    k_node_dot2<<<nb_waveN, 256, 0, stream>>>(xA, gate_align_w, gate_align_w, sN, tN, N, 0);
    k_gate_gather<<<nb_waveN, 256, 0, stream>>>(u, ea, row, csrc, ceid,
                                                gate_nl_w, gate_align_w, gate_align_b,
                                                sN, Agg, N);
    k_node_update<<<nb_node64, 512, 0, stream>>>(Agg, xA, gate_attend_w, gate_attend_b,
                                                 gru_wih, gru_whh, gru_bih, gru_bhh, xB, N);

    // ---- GAT layer 0 (xB -> xD) ----
    k_node_dot2<<<nb_waveN, 256, 0, stream>>>(xB, conv_align_w, conv_align_w + 64, sN, tN, N, 1);
    k_gat_gather<<<nb_waveN, 256, 0, stream>>>(row, csrc, xB, sN, tN, conv_align_b, Agg, N);
    k_node_update<<<nb_node64, 512, 0, stream>>>(Agg, xB, conv_attend_w, conv_attend_b,
                                                 gru_wih + 12288, gru_whh + 12288,
                                                 gru_bih + 192, gru_bhh + 192, xD, N);

    // ---- GAT layer 1 (xD -> xA) ----
    k_node_dot2<<<nb_waveN, 256, 0, stream>>>(xD, conv_align_w + 128, conv_align_w + 192, sN, tN, N, 1);
    k_gat_gather<<<nb_waveN, 256, 0, stream>>>(row, csrc, xD, sN, tN, conv_align_b + 1, Agg, N);
    k_node_update<<<nb_node64, 512, 0, stream>>>(Agg, xD, conv_attend_w + 4096, conv_attend_b + 64,
                                                 gru_wih + 24576, gru_whh + 24576,
                                                 gru_bih + 384, gru_bhh + 384, xA, N);

    // ---- molecule readout ----
    k_seg_sum_relu<<<nb_waveG, 256, 0, stream>>>(xA, gst, outS, G);

    const float* cachedP[2] = { xD, xA };
    float* sIn = outS; float* sOut = outS2;
    for (int t = 0; t < 2; ++t) {
        k_mol_dots<<<nb_waveN, 256, 0, stream>>>(xA, cachedP[t], mol_align_w, dd, N);
        k_mol_gather<<<nb_waveG, 256, 0, stream>>>(xA, cachedP[t], sIn, gst, dd,
                                                   mol_align_w, mol_align_b, aggG, G);
        k_node_update<<<nb_nodeG, 512, 0, stream>>>(aggG, sIn, mol_attend_w, mol_attend_b,
                                                    mol_wih, mol_whh, mol_bih, mol_bhh, sOut, G);
        float* tmp = sIn; sIn = sOut; sOut = tmp;
    }

    k_lin2<<<nb_waveG, 256, 0, stream>>>(sIn, lin2_w, lin2_b, out, G);
}

// Round 5
// 1560.534 us; speedup vs baseline: 8.1485x; 1.0356x over previous
//
#include <hip/hip_runtime.h>
#include <math.h>

#define NPAD 65

// ---------- small device helpers ----------
__device__ __forceinline__ float leaky(float x) { return x > 0.f ? x : 0.01f * x; }
__device__ __forceinline__ float eluf(float x)  { return x > 0.f ? x : (__expf(x) - 1.f); }
__device__ __forceinline__ float sigm(float x)  { return 1.f / (1.f + __expf(-x)); }
__device__ __forceinline__ float tanhfast(float x) { return 1.f - 2.f / (__expf(2.f * x) + 1.f); }

__device__ __forceinline__ float bcastf(float v, int k) {
    return __uint_as_float((unsigned)__builtin_amdgcn_readlane((int)__float_as_uint(v), k));
}
__device__ __forceinline__ int bcasti(int v, int k) {
    return __builtin_amdgcn_readlane(v, k);
}
__device__ __forceinline__ float wredsum(float v) {
    #pragma unroll
    for (int off = 32; off; off >>= 1) v += __shfl_xor(v, off);
    return v;
}
__device__ __forceinline__ float wredmax(float v) {
    #pragma unroll
    for (int off = 32; off; off >>= 1) v = fmaxf(v, __shfl_xor(v, off));
    return v;
}

// ================= CSR build =================
__global__ __launch_bounds__(256) void k_hist(const int* __restrict__ ei, int* __restrict__ deg, int E_) {
    int e = blockIdx.x * 256 + threadIdx.x;
    if (e < E_) atomicAdd(&deg[ei[E_ + e]], 1);
}

__global__ __launch_bounds__(256) void k_scan1(const int* __restrict__ deg, int* __restrict__ bsum, int N_) {
    __shared__ int s[256];
    int i = blockIdx.x * 256 + threadIdx.x;
    s[threadIdx.x] = (i < N_) ? deg[i] : 0;
    __syncthreads();
    for (int off = 128; off; off >>= 1) {
        if (threadIdx.x < off) s[threadIdx.x] += s[threadIdx.x + off];
        __syncthreads();
    }
    if (threadIdx.x == 0) bsum[blockIdx.x] = s[0];
}

// parallel exclusive scan of block sums (single block, chunked w/ carry)
__global__ __launch_bounds__(512) void k_scan2(int* __restrict__ bsum, int nb) {
    __shared__ int s[512];
    __shared__ int carry_s;
    if (threadIdx.x == 0) carry_s = 0;
    __syncthreads();
    for (int base = 0; base < nb; base += 512) {
        int t = threadIdx.x;
        int idx = base + t;
        int v = (idx < nb) ? bsum[idx] : 0;
        s[t] = v;
        __syncthreads();
        #pragma unroll
        for (int off = 1; off < 512; off <<= 1) {
            int u = (t >= off) ? s[t - off] : 0;
            __syncthreads();
            s[t] += u;
            __syncthreads();
        }
        int carry = carry_s;
        if (idx < nb) bsum[idx] = carry + s[t] - v;   // exclusive
        __syncthreads();
        if (t == 0) carry_s = carry + s[511];
        __syncthreads();
    }
}

__global__ __launch_bounds__(256) void k_scan3(const int* __restrict__ deg, const int* __restrict__ bsum,
                                               int* __restrict__ row, int* __restrict__ cur, int N_, int E_) {
    __shared__ int s[256];
    int i = blockIdx.x * 256 + threadIdx.x;
    int d = (i < N_) ? deg[i] : 0;
    s[threadIdx.x] = d;
    __syncthreads();
    for (int off = 1; off < 256; off <<= 1) {
        int v = (threadIdx.x >= off) ? s[threadIdx.x - off] : 0;
        __syncthreads();
        s[threadIdx.x] += v;
        __syncthreads();
    }
    if (i < N_) {
        int ex = bsum[blockIdx.x] + s[threadIdx.x] - d;
        row[i] = ex; cur[i] = ex;
    }
    if (i == N_ - 1) row[N_] = E_;
}

__global__ __launch_bounds__(256) void k_scatter(const int* __restrict__ ei, int* __restrict__ cur,
                                                 int* __restrict__ csrc, int* __restrict__ ceid, int E_) {
    int e = blockIdx.x * 256 + threadIdx.x;
    if (e >= E_) return;
    int dst = ei[E_ + e];
    int slot = atomicAdd(&cur[dst], 1);
    csrc[slot] = ei[e];
    ceid[slot] = e;
}

__global__ __launch_bounds__(256) void k_gbounds(const int* __restrict__ batch, int* __restrict__ gst,
                                                 int N_, int G_) {
    int i = blockIdx.x * 256 + threadIdx.x;
    if (i >= N_) return;
    int b = batch[i];
    int prev = (i == 0) ? -1 : batch[i - 1];
    for (int g = prev + 1; g <= b; ++g) gst[g] = i;
    if (i == N_ - 1) { for (int g = b + 1; g <= G_; ++g) gst[g] = N_; }
}

// ---------- dense64: out = act(in @ w^T + b), w row-stride = wstride ----------
__global__ __launch_bounds__(256) void k_dense64(
    const float* __restrict__ in, const float* __restrict__ w, int wstride,
    const float* __restrict__ b, float* __restrict__ outp, int M, int act)
{
    __shared__ float ti[64 * NPAD];
    __shared__ float to[64 * NPAD];
    int r0 = blockIdx.x * 64;
    for (int i = threadIdx.x; i < 4096; i += 256) {
        int r = i >> 6, c = i & 63; int gr = r0 + r;
        ti[r * NPAD + c] = (gr < M) ? in[(size_t)gr * 64 + c] : 0.f;
    }
    __syncthreads();
    int n = threadIdx.x & 63;
    int jl = __builtin_amdgcn_readfirstlane((threadIdx.x >> 6) << 4);
    float acc[16];
    #pragma unroll
    for (int jj = 0; jj < 16; ++jj) acc[jj] = b[jl + jj];
    for (int kc = 0; kc < 64; kc += 16) {
        float xr[16];
        #pragma unroll
        for (int i = 0; i < 16; ++i) xr[i] = ti[n * NPAD + kc + i];
        #pragma unroll
        for (int jj = 0; jj < 16; ++jj) {
            const float* wr = w + (jl + jj) * wstride + kc;
            #pragma unroll
            for (int i = 0; i < 16; ++i) acc[jj] = fmaf(wr[i], xr[i], acc[jj]);
        }
    }
    #pragma unroll
    for (int jj = 0; jj < 16; ++jj) {
        float v = acc[jj];
        to[n * NPAD + jl + jj] = act ? leaky(v) : v;
    }
    __syncthreads();
    for (int i = threadIdx.x; i < 4096; i += 256) {
        int r = i >> 6, c = i & 63; int gr = r0 + r;
        if (gr < M) outp[(size_t)gr * 64 + c] = to[r * NPAD + c];
    }
}

// ---------- per-node dot(s) with align vectors ----------
__global__ __launch_bounds__(256) void k_node_dot2(
    const float* __restrict__ x, const float* __restrict__ wa,
    const float* __restrict__ wb, float* __restrict__ s,
    float* __restrict__ t, int n, int two)
{
    int gt = blockIdx.x * 256 + threadIdx.x;
    int wid = gt >> 6, lane = threadIdx.x & 63;
    if (wid >= n) return;
    float xv = x[(size_t)wid * 64 + lane];
    float a = xv * wa[lane];
    float bb = two ? xv * wb[lane] : 0.f;
    #pragma unroll
    for (int off = 32; off; off >>= 1) {
        a  += __shfl_down(a, off);
        bb += __shfl_down(bb, off);
    }
    if (lane == 0) { s[wid] = a; if (two) t[wid] = bb; }
}

// ---------- GATE layer: wave per dst node, online softmax gather ----------
__global__ __launch_bounds__(256) void k_gate_gather(
    const float* __restrict__ u, const float* __restrict__ ea,
    const int* __restrict__ row, const int* __restrict__ csrc, const int* __restrict__ ceid,
    const float* __restrict__ wnl,
    const float* __restrict__ gaw, const float* __restrict__ gab,
    const float* __restrict__ sarr, float* __restrict__ Agg, int N_)
{
    int wid = (blockIdx.x * 256 + threadIdx.x) >> 6;
    int lane = threadIdx.x & 63;
    if (wid >= N_) return;
    float w2[16];
    #pragma unroll
    for (int k = 0; k < 16; ++k) w2[k] = wnl[lane * 80 + 64 + k];
    float g2 = gaw[64 + lane];
    float gb = gab[0];
    float sdst = sarr[wid];
    int beg = row[wid], end = row[wid + 1];
    float m = -INFINITY, d = 0.f, S = 0.f;
    for (int cs = beg; cs < end; cs += 64) {
        int cnt = min(64, end - cs);
        int src_l = 0, eid_l = 0;
        if (lane < cnt) { src_l = csrc[cs + lane]; eid_l = ceid[cs + lane]; }
        for (int l = 0; l < cnt; ++l) {
            int src = bcasti(src_l, l), eid = bcasti(eid_l, l);
            float acc = u[(size_t)src * 64 + lane];
            const float* er = ea + (size_t)eid * 16;
            #pragma unroll
            for (int k = 0; k < 16; ++k) acc = fmaf(er[k], w2[k], acc);
            float xj = leaky(acc);
            float t = wredsum(xj * g2);
            float sc = leaky(sdst + t + gb);
            float mn = fmaxf(m, sc);
            float c = __expf(m - mn), w = __expf(sc - mn);
            S = S * c + w * xj;
            d = d * c + w;
            m = mn;
        }
    }
    Agg[(size_t)wid * 64 + lane] = S / (d + 1e-16f);
}

// ---------- GAT layer: wave per dst node, chunked online softmax gather ----------
__global__ __launch_bounds__(256) void k_gat_gather(
    const int* __restrict__ row, const int* __restrict__ csrc,
    const float* __restrict__ x, const float* __restrict__ sarr,
    const float* __restrict__ tarr, const float* __restrict__ cb,
    float* __restrict__ Agg, int N_)
{
    int wid = (blockIdx.x * 256 + threadIdx.x) >> 6;
    int lane = threadIdx.x & 63;
    if (wid >= N_) return;
    float sdst = sarr[wid];
    float cbv = cb[0];
    int beg = row[wid], end = row[wid + 1];
    float m = -INFINITY, d = 0.f, S = 0.f;
    for (int cs = beg; cs < end; cs += 64) {
        int cnt = min(64, end - cs);
        float sc_l = -INFINITY; int src_l = 0;
        if (lane < cnt) {
            src_l = csrc[cs + lane];
            sc_l = leaky(sdst + tarr[src_l] + cbv);
        }
        float cmax = wredmax(sc_l);
        float mn = fmaxf(m, cmax);
        float c = __expf(m - mn);
        float w_l = __expf(sc_l - mn);
        d = d * c + wredsum(w_l);
        S *= c;
        int l = 0;
        for (; l + 4 <= cnt; l += 4) {
            int s0 = bcasti(src_l, l), s1 = bcasti(src_l, l + 1);
            int s2 = bcasti(src_l, l + 2), s3 = bcasti(src_l, l + 3);
            float w0 = bcastf(w_l, l), w1 = bcastf(w_l, l + 1);
            float w2 = bcastf(w_l, l + 2), w3 = bcastf(w_l, l + 3);
            float r0 = x[(size_t)s0 * 64 + lane];
            float r1 = x[(size_t)s1 * 64 + lane];
            float r2 = x[(size_t)s2 * 64 + lane];
            float r3 = x[(size_t)s3 * 64 + lane];
            S = fmaf(w0, r0, S); S = fmaf(w1, r1, S);
            S = fmaf(w2, r2, S); S = fmaf(w3, r3, S);
        }
        for (; l < cnt; ++l) {
            float wl = bcastf(w_l, l);
            int srcl = bcasti(src_l, l);
            S = fmaf(wl, x[(size_t)srcl * 64 + lane], S);
        }
        m = mn;
    }
    Agg[(size_t)wid * 64 + lane] = S / (d + 1e-16f);
}

// ---------- fused node update (512 thr, 8 j/thread, fused r/z accumulators) ----------
// h = elu(Agg@Wa^T + ba); out = relu(GRU(h, x)); optionally also emits
// sout[n]=out.dwa, tout[n]=out.dwb (align dots for the NEXT layer).
// launch_bounds(512,4): 4 waves/EU min -> 128-VGPR cap, no spills (was 32 VGPR + spill)
__global__ __launch_bounds__(512, 4) void k_node_update(
    const float* __restrict__ agg, const float* __restrict__ xold,
    const float* __restrict__ wa, const float* __restrict__ ba,
    const float* __restrict__ wih, const float* __restrict__ whh,
    const float* __restrict__ bih, const float* __restrict__ bhh,
    float* __restrict__ xout, int M,
    const float* __restrict__ dwa, const float* __restrict__ dwb,
    float* __restrict__ sout, float* __restrict__ tout)
{
    __shared__ float tA[64 * NPAD];   // agg tile, then h tile, then out tile
    __shared__ float tX[64 * NPAD];   // xold tile
    int r0 = blockIdx.x * 64;
    for (int i = threadIdx.x; i < 4096; i += 512) {
        int r = i >> 6, c = i & 63; int gr = r0 + r;
        float av = 0.f, xv = 0.f;
        if (gr < M) { av = agg[(size_t)gr * 64 + c]; xv = xold[(size_t)gr * 64 + c]; }
        tA[r * NPAD + c] = av; tX[r * NPAD + c] = xv;
    }
    __syncthreads();
    int n = threadIdx.x & 63;
    int jl = __builtin_amdgcn_readfirstlane((threadIdx.x >> 6) << 3);  // 0..56

    // Phase B: h[jl..jl+8) = elu(Agg @ Wa^T + ba)
    float hv[8];
    {
        float acc[8];
        #pragma unroll
        for (int jj = 0; jj < 8; ++jj) acc[jj] = ba[jl + jj];
        for (int kc = 0; kc < 64; kc += 16) {
            float ar[16];
            #pragma unroll
            for (int i = 0; i < 16; ++i) ar[i] = tA[n * NPAD + kc + i];
            #pragma unroll
            for (int jj = 0; jj < 8; ++jj) {
                const float* wr = wa + (jl + jj) * 64 + kc;
                #pragma unroll
                for (int i = 0; i < 16; ++i) acc[jj] = fmaf(wr[i], ar[i], acc[jj]);
            }
        }
        #pragma unroll
        for (int jj = 0; jj < 8; ++jj) hv[jj] = eluf(acc[jj]);
    }
    __syncthreads();          // all phase-B reads of tA done
    #pragma unroll
    for (int jj = 0; jj < 8; ++jj) tA[n * NPAD + jl + jj] = hv[jj];
    __syncthreads();          // h tile visible

    // Phase C: GRU. r/z accumulate both input+hidden streams in one register.
    float a_r[8], a_z[8], a_n[8], a_h[8];
    #pragma unroll
    for (int jj = 0; jj < 8; ++jj) {
        a_r[jj] = bih[jl + jj] + bhh[jl + jj];
        a_z[jj] = bih[64 + jl + jj] + bhh[64 + jl + jj];
        a_n[jj] = bih[128 + jl + jj];
        a_h[jj] = bhh[128 + jl + jj];
    }
    for (int kc = 0; kc < 64; kc += 8) {
        float hr_[8], xr_[8];
        #pragma unroll
        for (int i = 0; i < 8; ++i) { hr_[i] = tA[n * NPAD + kc + i]; xr_[i] = tX[n * NPAD + kc + i]; }
        #pragma unroll
        for (int jj = 0; jj < 8; ++jj) {
            const float* w1 = wih + (jl + jj) * 64 + kc;          // r, input
            const float* w4 = whh + (jl + jj) * 64 + kc;          // r, hidden
            const float* w2 = wih + (64 + jl + jj) * 64 + kc;     // z, input
            const float* w5 = whh + (64 + jl + jj) * 64 + kc;     // z, hidden
            const float* w3 = wih + (128 + jl + jj) * 64 + kc;    // n, input
            const float* w6 = whh + (128 + jl + jj) * 64 + kc;    // n, hidden
            #pragma unroll
            for (int i = 0; i < 8; ++i) {
                a_r[jj] = fmaf(w1[i], hr_[i], a_r[jj]);
                a_r[jj] = fmaf(w4[i], xr_[i], a_r[jj]);
                a_z[jj] = fmaf(w2[i], hr_[i], a_z[jj]);
                a_z[jj] = fmaf(w5[i], xr_[i], a_z[jj]);
                a_n[jj] = fmaf(w3[i], hr_[i], a_n[jj]);
                a_h[jj] = fmaf(w6[i], xr_[i], a_h[jj]);
            }
        }
    }
    #pragma unroll
    for (int jj = 0; jj < 8; ++jj) {
        float r = sigm(a_r[jj]);
        float z = sigm(a_z[jj]);
        float nn = tanhfast(a_n[jj] + r * a_h[jj]);
        float xo = tX[n * NPAD + jl + jj];
        float v = (1.f - z) * nn + z * xo;
        hv[jj] = fmaxf(v, 0.f);
    }
    __syncthreads();          // all phase-C reads of tA done
    #pragma unroll
    for (int jj = 0; jj < 8; ++jj) tA[n * NPAD + jl + jj] = hv[jj];
    __syncthreads();
    for (int i = threadIdx.x; i < 4096; i += 512) {
        int r = i >> 6, c = i & 63; int gr = r0 + r;
        if (gr < M) xout[(size_t)gr * 64 + c] = tA[r * NPAD + c];
    }

    // Fused align dots for the next layer: sout[n]=out.dwa, tout[n]=out.dwb
    if (sout != nullptr) {
        float wav = dwa[n], wbv = dwb[n];
        int rw = threadIdx.x >> 6;        // wave id 0..7
        #pragma unroll
        for (int q = 0; q < 8; ++q) {
            int r = rw + 8 * q; int gr = r0 + r;
            float val = tA[r * NPAD + n];
            float a = wredsum(val * wav);
            float bb = wredsum(val * wbv);
            if (n == 0 && gr < M) { sout[gr] = a; tout[gr] = bb; }
        }
    }
}

// ---------- readout: wave per graph, contiguous segment sum + relu ----------
__global__ __launch_bounds__(256) void k_seg_sum_relu(
    const float* __restrict__ x, const int* __restrict__ gst,
    float* __restrict__ outp, int G_)
{
    int g = (blockIdx.x * 256 + threadIdx.x) >> 6;
    int lane = threadIdx.x & 63;
    if (g >= G_) return;
    float S = 0.f;
    int end = gst[g + 1];
    for (int i = gst[g]; i < end; ++i) S += x[(size_t)i * 64 + lane];
    outp[(size_t)g * 64 + lane] = fmaxf(S, 0.f);
}

// ---------- mol: per-node dot of mix with align part 2 ----------
__global__ __launch_bounds__(256) void k_mol_dots(
    const float* __restrict__ xf, const float* __restrict__ cach,
    const float* __restrict__ maw, float* __restrict__ dd, int n)
{
    int wid = (blockIdx.x * 256 + threadIdx.x) >> 6;
    int lane = threadIdx.x & 63;
    if (wid >= n) return;
    float mix = 0.5f * (xf[(size_t)wid * 64 + lane] + cach[(size_t)wid * 64 + lane]);
    float v = wredsum(mix * maw[64 + lane]);
    if (lane == 0) dd[wid] = v;
}

// ---------- molecule attention: wave per graph, chunked online softmax ----------
__global__ __launch_bounds__(256) void k_mol_gather(
    const float* __restrict__ xf, const float* __restrict__ cach,
    const float* __restrict__ stateIn, const int* __restrict__ gst,
    const float* __restrict__ dd,
    const float* __restrict__ maw, const float* __restrict__ mab,
    float* __restrict__ Agg, int G_)
{
    int g = (blockIdx.x * 256 + threadIdx.x) >> 6;
    int lane = threadIdx.x & 63;
    if (g >= G_) return;
    float o = stateIn[(size_t)g * 64 + lane];
    float og = wredsum(o * maw[lane]);
    float mb = mab[0];
    int beg = gst[g], end = gst[g + 1];
    float m = -INFINITY, d = 0.f, S = 0.f;
    for (int cs = beg; cs < end; cs += 64) {
        int cnt = min(64, end - cs);
        float sc_l = -INFINITY;
        if (lane < cnt) sc_l = leaky(og + dd[cs + lane] + mb);
        float cmax = wredmax(sc_l);
        float mn = fmaxf(m, cmax);
        float c = __expf(m - mn);
        float w_l = __expf(sc_l - mn);
        d = d * c + wredsum(w_l);
        S *= c;
        int l = 0;
        for (; l + 4 <= cnt; l += 4) {
            float w0 = bcastf(w_l, l), w1 = bcastf(w_l, l + 1);
            float w2 = bcastf(w_l, l + 2), w3 = bcastf(w_l, l + 3);
            size_t r = (size_t)(cs + l) * 64 + lane;
            float m0 = 0.5f * (xf[r] + cach[r]);
            float m1 = 0.5f * (xf[r + 64] + cach[r + 64]);
            float m2 = 0.5f * (xf[r + 128] + cach[r + 128]);
            float m3 = 0.5f * (xf[r + 192] + cach[r + 192]);
            S = fmaf(w0, m0, S); S = fmaf(w1, m1, S);
            S = fmaf(w2, m2, S); S = fmaf(w3, m3, S);
        }
        for (; l < cnt; ++l) {
            float wl = bcastf(w_l, l);
            size_t r = (size_t)(cs + l) * 64 + lane;
            S = fmaf(wl, 0.5f * (xf[r] + cach[r]), S);
        }
        m = mn;
    }
    Agg[(size_t)g * 64 + lane] = S / (d + 1e-16f);
}

// ---------- final: out[g] = state[g].lin2_w + lin2_b ----------
__global__ __launch_bounds__(256) void k_lin2(
    const float* __restrict__ st, const float* __restrict__ w,
    const float* __restrict__ b, float* __restrict__ outp, int g)
{
    int gt = blockIdx.x * 256 + threadIdx.x;
    int wid = gt >> 6, lane = threadIdx.x & 63;
    if (wid >= g) return;
    float v = st[(size_t)wid * 64 + lane] * w[lane];
    #pragma unroll
    for (int off = 32; off; off >>= 1) v += __shfl_down(v, off);
    if (lane == 0) outp[wid] = v + b[0];
}

// =====================================================================
extern "C" void kernel_launch(void* const* d_in, const int* in_sizes, int n_in,
                              void* d_out, int out_size, void* d_ws, size_t ws_size,
                              hipStream_t stream) {
    const float* raw           = (const float*)d_in[0];
    const int*   ei            = (const int*)d_in[1];
    const float* ea            = (const float*)d_in[2];
    const int*   batch         = (const int*)d_in[3];
    const float* lin1_w        = (const float*)d_in[4];
    const float* lin1_b        = (const float*)d_in[5];
    const float* gate_nl_w     = (const float*)d_in[6];
    const float* gate_nl_b     = (const float*)d_in[7];
    const float* gate_align_w  = (const float*)d_in[8];
    const float* gate_align_b  = (const float*)d_in[9];
    const float* gate_attend_w = (const float*)d_in[10];
    const float* gate_attend_b = (const float*)d_in[11];
    const float* conv_align_w  = (const float*)d_in[12];
    const float* conv_align_b  = (const float*)d_in[13];
    const float* conv_attend_w = (const float*)d_in[14];
    const float* conv_attend_b = (const float*)d_in[15];
    const float* gru_wih       = (const float*)d_in[16];
    const float* gru_whh       = (const float*)d_in[17];
    const float* gru_bih       = (const float*)d_in[18];
    const float* gru_bhh       = (const float*)d_in[19];
    const float* mol_align_w   = (const float*)d_in[20];
    const float* mol_align_b   = (const float*)d_in[21];
    const float* mol_attend_w  = (const float*)d_in[22];
    const float* mol_attend_b  = (const float*)d_in[23];
    const float* mol_wih       = (const float*)d_in[24];
    const float* mol_whh       = (const float*)d_in[25];
    const float* mol_bih       = (const float*)d_in[26];
    const float* mol_bhh       = (const float*)d_in[27];
    const float* lin2_w        = (const float*)d_in[28];
    const float* lin2_b        = (const float*)d_in[29];
    float* out = (float*)d_out;

    const int N = in_sizes[3];
    const int E = in_sizes[1] / 2;
    const int G = out_size;
    const size_t N64 = (size_t)N * 64;
    const size_t G64 = (size_t)G * 64;

    // ---- workspace layout ----
    float* f = (float*)d_ws;
    float* xA    = f;
    float* xB    = xA + N64;
    float* xD    = xB + N64;
    float* Agg   = xD + N64;
    float* u     = Agg + N64;
    float* sN    = u + N64;
    float* tN    = sN + N;
    float* dd    = tN + N;
    float* outS  = dd + N;
    float* outS2 = outS + G64;
    float* aggG  = outS2 + G64;
    int* row  = (int*)(aggG + G64);
    int* csrc = row + (N + 1);
    int* ceid = csrc + E;
    int* bsum = ceid + E;
    int* gst  = bsum + 512;
    int* deg = (int*)Agg;
    int* cur = deg + N;

    const int nb_node64 = (N + 63) / 64;
    const int nb_edge   = (E + 255) / 256;
    const int nb_nodes  = (N + 255) / 256;
    const int nb_waveN  = (N + 3) / 4;
    const int nb_waveG  = (G + 3) / 4;
    const int nb_nodeG  = (G + 63) / 64;

    // ---- CSR build ----
    hipMemsetAsync(deg, 0, (size_t)N * 4, stream);
    k_hist<<<nb_edge, 256, 0, stream>>>(ei, deg, E);
    k_scan1<<<nb_nodes, 256, 0, stream>>>(deg, bsum, N);
    k_scan2<<<1, 512, 0, stream>>>(bsum, nb_nodes);
    k_scan3<<<nb_nodes, 256, 0, stream>>>(deg, bsum, row, cur, N, E);
    k_scatter<<<nb_edge, 256, 0, stream>>>(ei, cur, csrc, ceid, E);
    k_gbounds<<<nb_nodes, 256, 0, stream>>>(batch, gst, N, G);

    // ---- lin1 + gate node-part precompute ----
    k_dense64<<<nb_node64, 256, 0, stream>>>(raw, lin1_w, 64, lin1_b, xA, N, 1);
    k_dense64<<<nb_node64, 256, 0, stream>>>(raw, gate_nl_w, 80, gate_nl_b, u, N, 0);

    // ---- layer 0: GATEConv (xA -> xB); emits align dots for GAT layer 0 ----
    k_node_dot2<<<nb_waveN, 256, 0, stream>>>(xA, gate_align_w, gate_align_w, sN, tN, N, 0);
    k_gate_gather<<<nb_waveN, 256, 0, stream>>>(u, ea, row, csrc, ceid,
                                                gate_nl_w, gate_align_w, gate_align_b,
                                                sN, Agg, N);
    k_node_update<<<nb_node64, 512, 0, stream>>>(Agg, xA, gate_attend_w, gate_attend_b,
                                                 gru_wih, gru_whh, gru_bih, gru_bhh, xB, N,
                                                 conv_align_w, conv_align_w + 64, sN, tN);

    // ---- GAT layer 0 (xB -> xD); emits align dots for GAT layer 1 ----
    k_gat_gather<<<nb_waveN, 256, 0, stream>>>(row, csrc, xB, sN, tN, conv_align_b, Agg, N);
    k_node_update<<<nb_node64, 512, 0, stream>>>(Agg, xB, conv_attend_w, conv_attend_b,
                                                 gru_wih + 12288, gru_whh + 12288,
                                                 gru_bih + 192, gru_bhh + 192, xD, N,
                                                 conv_align_w + 128, conv_align_w + 192, sN, tN);

    // ---- GAT layer 1 (xD -> xA) ----
    k_gat_gather<<<nb_waveN, 256, 0, stream>>>(row, csrc, xD, sN, tN, conv_align_b + 1, Agg, N);
    k_node_update<<<nb_node64, 512, 0, stream>>>(Agg, xD, conv_attend_w + 4096, conv_attend_b + 64,
                                                 gru_wih + 24576, gru_whh + 24576,
                                                 gru_bih + 384, gru_bhh + 384, xA, N,
                                                 nullptr, nullptr, nullptr, nullptr);

    // ---- molecule readout ----
    k_seg_sum_relu<<<nb_waveG, 256, 0, stream>>>(xA, gst, outS, G);

    const float* cachedP[2] = { xD, xA };
    float* sIn = outS; float* sOut = outS2;
    for (int t = 0; t < 2; ++t) {
        k_mol_dots<<<nb_waveN, 256, 0, stream>>>(xA, cachedP[t], mol_align_w, dd, N);
        k_mol_gather<<<nb_waveG, 256, 0, stream>>>(xA, cachedP[t], sIn, gst, dd,
                                                   mol_align_w, mol_align_b, aggG, G);
        k_node_update<<<nb_nodeG, 512, 0, stream>>>(aggG, sIn, mol_attend_w, mol_attend_b,
                                                    mol_wih, mol_whh, mol_bih, mol_bhh, sOut, G,
                                                    nullptr, nullptr, nullptr, nullptr);
        float* tmp = sIn; sIn = sOut; sOut = tmp;
    }

    k_lin2<<<nb_waveG, 256, 0, stream>>>(sIn, lin2_w, lin2_b, out, G);
}